// Round 2
// baseline (4877.651 us; speedup 1.0000x reference)
//
#include <hip/hip_runtime.h>
#include <math.h>

static constexpr int Bsz = 4, Tn = 1024, Dn = 512, Hn = 8, Fn = 2048, Kw = 31, Dk = 64;
static constexpr size_t N_OUT  = (size_t)Bsz * Tn * Dn;   // 2,097,152
static constexpr size_t N_POSK = (size_t)Tn * Tn * Dk;    // 67,108,864
static constexpr size_t N_MASK = (size_t)Bsz * Tn * Tn;   // 4,194,304

// ---------------------------------------------------------------------------
// LayerNorm (one 256-thread block per row of D=512), optional fused GLU
// y = (x-mean)*rsqrt(var+eps)*g + b ; if GLU: y=(w0*y+c0)*sigmoid(w1*y+c1)
// ---------------------------------------------------------------------------
template <int GLU>
__global__ __launch_bounds__(256) void ln_kernel(
    const float* __restrict__ x, const float* __restrict__ g,
    const float* __restrict__ b, float* __restrict__ y,
    const float* __restrict__ pw1w, const float* __restrict__ pw1b) {
  const int row = blockIdx.x;
  const float* xr = x + (size_t)row * Dn;
  float* yr = y + (size_t)row * Dn;
  const int tid = threadIdx.x, wid = tid >> 6, lane = tid & 63;

  __shared__ float red[4];
  __shared__ float bc[2];

  float v0 = xr[tid], v1 = xr[tid + 256];
  float s = v0 + v1;
#pragma unroll
  for (int off = 32; off; off >>= 1) s += __shfl_xor(s, off);
  if (lane == 0) red[wid] = s;
  __syncthreads();
  if (tid == 0) bc[0] = (red[0] + red[1] + red[2] + red[3]) * (1.0f / Dn);
  __syncthreads();
  const float m = bc[0];
  const float d0 = v0 - m, d1 = v1 - m;
  float s2 = d0 * d0 + d1 * d1;
#pragma unroll
  for (int off = 32; off; off >>= 1) s2 += __shfl_xor(s2, off);
  if (lane == 0) red[wid] = s2;
  __syncthreads();
  if (tid == 0)
    bc[1] = rsqrtf((red[0] + red[1] + red[2] + red[3]) * (1.0f / Dn) + 1e-5f);
  __syncthreads();
  const float r = bc[1];

  float o0 = d0 * r * g[tid] + b[tid];
  float o1 = d1 * r * g[tid + 256] + b[tid + 256];
  if (GLU) {
    const float w0 = pw1w[0], w1 = pw1w[1], c0 = pw1b[0], c1 = pw1b[1];
    o0 = (w0 * o0 + c0) * (1.0f / (1.0f + expf(-(w1 * o0 + c1))));
    o1 = (w0 * o1 + c0) * (1.0f / (1.0f + expf(-(w1 * o1 + c1))));
  }
  yr[tid] = o0;
  yr[tid + 256] = o1;
}

// ---------------------------------------------------------------------------
// fp32 tiled GEMM: C(M,N) = epilogue(A(M,K) @ W(K,N) + bias[n])
// MODE 0: relu(acc+bias)          -> C
// MODE 1: res + 0.5f*(acc+bias)   -> C
// MODE 2: acc+bias                -> C
// MODE 3: res + acc + bias        -> C
// BM=BN=128, BK=16, 256 threads, 8x8 per thread (split 4+4 for LDS banking)
// ---------------------------------------------------------------------------
template <int MODE>
__global__ __launch_bounds__(256) void gemm_kernel(
    const float* __restrict__ A, const float* __restrict__ W,
    const float* __restrict__ bias, const float* __restrict__ res,
    float* __restrict__ C, int M, int N, int Kdim) {
  __shared__ float As[16][129];
  __shared__ float Bs[16][128];
  const int bm = blockIdx.y * 128, bn = blockIdx.x * 128;
  const int tid = threadIdx.x;
  const int tx = tid & 15, ty = tid >> 4;

  float acc[8][8] = {};

  for (int k0 = 0; k0 < Kdim; k0 += 16) {
    // A tile (128 rows x 16 cols), stored transposed As[k][m]
#pragma unroll
    for (int i = 0; i < 2; ++i) {
      int idx = tid + i * 256;  // float4 index, 512 total
      int r = idx >> 2, c4 = idx & 3;
      const float4 av =
          *(const float4*)(A + (size_t)(bm + r) * Kdim + k0 + c4 * 4);
      As[c4 * 4 + 0][r] = av.x;
      As[c4 * 4 + 1][r] = av.y;
      As[c4 * 4 + 2][r] = av.z;
      As[c4 * 4 + 3][r] = av.w;
    }
    // B tile (16 rows x 128 cols), direct Bs[k][n]
#pragma unroll
    for (int i = 0; i < 2; ++i) {
      int idx = tid + i * 256;
      int r = idx >> 5, c4 = idx & 31;
      *(float4*)&Bs[r][c4 * 4] =
          *(const float4*)(W + (size_t)(k0 + r) * N + bn + c4 * 4);
    }
    __syncthreads();
#pragma unroll
    for (int kk = 0; kk < 16; ++kk) {
      float a[8], bb[8];
#pragma unroll
      for (int i = 0; i < 4; ++i) {
        a[i] = As[kk][ty * 4 + i];
        a[4 + i] = As[kk][64 + ty * 4 + i];
      }
#pragma unroll
      for (int j = 0; j < 4; ++j) {
        bb[j] = Bs[kk][tx * 4 + j];
        bb[4 + j] = Bs[kk][64 + tx * 4 + j];
      }
#pragma unroll
      for (int i = 0; i < 8; ++i)
#pragma unroll
        for (int j = 0; j < 8; ++j) acc[i][j] += a[i] * bb[j];
    }
    __syncthreads();
  }

#pragma unroll
  for (int i = 0; i < 8; ++i) {
    int m = bm + ((i < 4) ? (ty * 4 + i) : (64 + ty * 4 + (i - 4)));
#pragma unroll
    for (int j = 0; j < 8; ++j) {
      int n = bn + ((j < 4) ? (tx * 4 + j) : (64 + tx * 4 + (j - 4)));
      float v = acc[i][j] + bias[n];
      if (MODE == 0) v = fmaxf(v, 0.0f);
      if (MODE == 1) v = res[(size_t)m * N + n] + 0.5f * v;
      if (MODE == 3) v = res[(size_t)m * N + n] + v;
      C[(size_t)m * N + n] = v;
    }
  }
}

// ---------------------------------------------------------------------------
// Fused rel-pos attention: one block (4 waves) per (t, b*H+h).
// scores[s] = (q . (k[s] + pos_k[t,s])) / sqrt(DK), masked, softmax, PV.
// q/k/v live in (B,T,D) layout with head-slice at column h*64.
// ---------------------------------------------------------------------------
__global__ __launch_bounds__(256) void attn_kernel(
    const float* __restrict__ qb, const float* __restrict__ kb,
    const float* __restrict__ vb, const float* __restrict__ pk,
    const int* __restrict__ mask, float* __restrict__ ctx) {
  const int blk = blockIdx.x;
  const int bh = blk & 31;  // b*H + h
  const int t = blk >> 5;
  const int b = bh >> 3, h = bh & 7;
  const int tid = threadIdx.x, wid = tid >> 6, lane = tid & 63;

  __shared__ float sc[Tn];
  __shared__ float red[4];
  __shared__ float bcv[2];
  __shared__ float cpart[4][Dk];

  const float qv = qb[((size_t)(b * Tn + t)) * Dn + h * Dk + lane];
  const float* krow = kb + (size_t)b * Tn * Dn + h * Dk + lane;
  const float* prow = pk + ((size_t)t * Tn) * Dk + lane;
  const int* mrow = mask + ((size_t)b * Tn + t) * Tn;
  const float scale = 0.125f;  // 1/sqrt(64)

  // phase 1: scores (one s per wave per iteration, wave-reduce the 64-d dot)
  for (int s = wid; s < Tn; s += 4) {
    float val = qv * (krow[(size_t)s * Dn] + prow[(size_t)s * Dk]);
#pragma unroll
    for (int off = 32; off; off >>= 1) val += __shfl_xor(val, off);
    if (lane == 0) sc[s] = (mrow[s] == 0) ? -3.0e38f : val * scale;
  }
  __syncthreads();

  // phase 2: softmax over sc[0..T)
  float mx = -3.4e38f;
  for (int i = tid; i < Tn; i += 256) mx = fmaxf(mx, sc[i]);
#pragma unroll
  for (int off = 32; off; off >>= 1) mx = fmaxf(mx, __shfl_xor(mx, off));
  if (lane == 0) red[wid] = mx;
  __syncthreads();
  if (tid == 0)
    bcv[0] = fmaxf(fmaxf(red[0], red[1]), fmaxf(red[2], red[3]));
  __syncthreads();
  mx = bcv[0];

  float ss = 0.0f;
  for (int i = tid; i < Tn; i += 256) {
    float scv = sc[i];
    float p = (scv <= -1.0e37f) ? 0.0f : __expf(scv - mx);
    sc[i] = p;
    ss += p;
  }
#pragma unroll
  for (int off = 32; off; off >>= 1) ss += __shfl_xor(ss, off);
  if (lane == 0) red[wid] = ss;
  __syncthreads();
  if (tid == 0)
    bcv[1] = 1.0f / fmaxf(red[0] + red[1] + red[2] + red[3], 1e-30f);
  __syncthreads();
  const float inv = bcv[1];

  // phase 3: ctx[d] = inv * sum_s p[s] * v[s,d]; each wave owns a quarter of s
  const float* vrow = vb + (size_t)b * Tn * Dn + h * Dk + lane;
  float accv = 0.0f;
  const int s0 = wid * 256;
  for (int s = s0; s < s0 + 256; ++s) accv += sc[s] * vrow[(size_t)s * Dn];
  cpart[wid][lane] = accv;
  __syncthreads();
  if (wid == 0) {
    float r =
        (cpart[0][lane] + cpart[1][lane] + cpart[2][lane] + cpart[3][lane]) *
        inv;
    ctx[((size_t)(b * Tn + t)) * Dn + h * Dk + lane] = r;
  }
}

// ---------------------------------------------------------------------------
// Depthwise conv1d (K=31, pad 15) + ReLU + pointwise2 + residual, in-place on x
// ---------------------------------------------------------------------------
__global__ __launch_bounds__(256) void conv_kernel(
    const float* __restrict__ y, const float* __restrict__ dw,
    const float* __restrict__ dwb, const float* __restrict__ pw2w,
    const float* __restrict__ pw2b, float* __restrict__ x) {
  const int bt = blockIdx.x;
  const int b = bt >> 10, t = bt & (Tn - 1);
  const int tid = threadIdx.x;
  const float w2 = pw2w[0], c2 = pw2b[0];

  for (int dd = tid; dd < Dn; dd += 256) {
    float acc = dwb[dd];
#pragma unroll
    for (int k = 0; k < Kw; ++k) {
      int s = t + k - 15;
      if (s >= 0 && s < Tn)
        acc += dw[dd * Kw + k] * y[((size_t)b * Tn + s) * Dn + dd];
    }
    acc = fmaxf(acc, 0.0f);
    size_t idx = ((size_t)b * Tn + t) * Dn + dd;
    x[idx] = x[idx] + w2 * acc + c2;
  }
}

// ---------------------------------------------------------------------------
// int32 -> float32 conversion (mask passthrough; harness reads out as fp32)
// ---------------------------------------------------------------------------
__global__ __launch_bounds__(256) void i2f_kernel(const int* __restrict__ in,
                                                  float* __restrict__ out,
                                                  size_t n4) {
  size_t i = (size_t)blockIdx.x * 256 + threadIdx.x;
  if (i < n4) {
    const int4 v = ((const int4*)in)[i];
    float4 f;
    f.x = (float)v.x;
    f.y = (float)v.y;
    f.z = (float)v.z;
    f.w = (float)v.w;
    ((float4*)out)[i] = f;
  }
}

// ---------------------------------------------------------------------------
extern "C" void kernel_launch(void* const* d_in, const int* in_sizes, int n_in,
                              void* d_out, int out_size, void* d_ws,
                              size_t ws_size, hipStream_t stream) {
  const float* x = (const float*)d_in[0];
  const float* pos_k = (const float*)d_in[1];
  const int* mask = (const int*)d_in[2];
  const float* fi_g = (const float*)d_in[3];
  const float* fi_b = (const float*)d_in[4];
  const float* fi_w1 = (const float*)d_in[5];
  const float* fi_b1 = (const float*)d_in[6];
  const float* fi_w2 = (const float*)d_in[7];
  const float* fi_b2 = (const float*)d_in[8];
  const float* at_g = (const float*)d_in[9];
  const float* at_b = (const float*)d_in[10];
  const float* wq = (const float*)d_in[11];
  const float* bq = (const float*)d_in[12];
  const float* wk = (const float*)d_in[13];
  const float* bk = (const float*)d_in[14];
  const float* wv = (const float*)d_in[15];
  const float* bv = (const float*)d_in[16];
  const float* wo = (const float*)d_in[17];
  const float* bo = (const float*)d_in[18];
  const float* cv_g = (const float*)d_in[19];
  const float* cv_b = (const float*)d_in[20];
  const float* pw1w = (const float*)d_in[21];
  const float* pw1b = (const float*)d_in[22];
  const float* dww = (const float*)d_in[23];
  const float* dwb = (const float*)d_in[24];
  const float* pw2w = (const float*)d_in[25];
  const float* pw2b = (const float*)d_in[26];
  const float* fo_g = (const float*)d_in[27];
  const float* fo_b = (const float*)d_in[28];
  const float* fo_w1 = (const float*)d_in[29];
  const float* fo_b1 = (const float*)d_in[30];
  const float* fo_w2 = (const float*)d_in[31];
  const float* fo_b2 = (const float*)d_in[32];
  const float* fl_g = (const float*)d_in[33];
  const float* fl_b = (const float*)d_in[34];

  float* out = (float*)d_out;
  float* ws = (float*)d_ws;

  // workspace layout (floats): xcur[2M] | y[2M] | U[8M]
  float* xcur = ws;
  float* y = ws + N_OUT;
  float* U = ws + 2 * N_OUT;
  float* hbuf = U;                 // (B*T, F) for FFN hidden
  float* qbuf = U;                 // (B,T,D)  — union with hbuf (disjoint in time)
  float* kbuf = U + N_OUT;
  float* vbuf = U + 2 * N_OUT;
  float* ctx = U + 3 * N_OUT;

  const int M = Bsz * Tn;  // 4096
  const dim3 blk256(256);
  const dim3 grid_rows(M);
  const dim3 gF(Fn / 128, M / 128);  // N=2048
  const dim3 gD(Dn / 128, M / 128);  // N=512

  // x -> xcur
  hipMemcpyAsync(xcur, x, N_OUT * sizeof(float), hipMemcpyDeviceToDevice,
                 stream);

  // macaron FFN-in: x += 0.5*(relu(LN(x)@w1+b1)@w2+b2)
  ln_kernel<0><<<grid_rows, blk256, 0, stream>>>(xcur, fi_g, fi_b, y, nullptr,
                                                 nullptr);
  gemm_kernel<0><<<gF, blk256, 0, stream>>>(y, fi_w1, fi_b1, nullptr, hbuf, M,
                                            Fn, Dn);
  gemm_kernel<1><<<gD, blk256, 0, stream>>>(hbuf, fi_w2, fi_b2, xcur, xcur, M,
                                            Dn, Fn);

  // attention
  ln_kernel<0><<<grid_rows, blk256, 0, stream>>>(xcur, at_g, at_b, y, nullptr,
                                                 nullptr);
  gemm_kernel<2><<<gD, blk256, 0, stream>>>(y, wq, bq, nullptr, qbuf, M, Dn,
                                            Dn);
  gemm_kernel<2><<<gD, blk256, 0, stream>>>(y, wk, bk, nullptr, kbuf, M, Dn,
                                            Dn);
  gemm_kernel<2><<<gD, blk256, 0, stream>>>(y, wv, bv, nullptr, vbuf, M, Dn,
                                            Dn);
  attn_kernel<<<dim3(Tn * 32), blk256, 0, stream>>>(qbuf, kbuf, vbuf, pos_k,
                                                    mask, ctx);
  gemm_kernel<3><<<gD, blk256, 0, stream>>>(ctx, wo, bo, xcur, xcur, M, Dn,
                                            Dn);

  // conv module
  ln_kernel<1><<<grid_rows, blk256, 0, stream>>>(xcur, cv_g, cv_b, y, pw1w,
                                                 pw1b);
  conv_kernel<<<grid_rows, blk256, 0, stream>>>(y, dww, dwb, pw2w, pw2b, xcur);

  // macaron FFN-out
  ln_kernel<0><<<grid_rows, blk256, 0, stream>>>(xcur, fo_g, fo_b, y, nullptr,
                                                 nullptr);
  gemm_kernel<0><<<gF, blk256, 0, stream>>>(y, fo_w1, fo_b1, nullptr, hbuf, M,
                                            Fn, Dn);
  gemm_kernel<1><<<gD, blk256, 0, stream>>>(hbuf, fo_w2, fo_b2, xcur, xcur, M,
                                            Dn, Fn);

  // final LN -> d_out[0]
  ln_kernel<0><<<grid_rows, blk256, 0, stream>>>(xcur, fl_g, fl_b, out,
                                                 nullptr, nullptr);

  // passthrough outputs: pos_k (fp32 bit-copy), mask (int32 -> fp32 convert)
  hipMemcpyAsync(out + N_OUT, pos_k, N_POSK * sizeof(float),
                 hipMemcpyDeviceToDevice, stream);
  i2f_kernel<<<dim3((N_MASK / 4 + 255) / 256), blk256, 0, stream>>>(
      mask, out + N_OUT + N_POSK, N_MASK / 4);
}

// Round 3
// 1879.181 us; speedup vs baseline: 2.5956x; 2.5956x over previous
//
#include <hip/hip_runtime.h>
#include <math.h>

static constexpr int Bsz = 4, Tn = 1024, Dn = 512, Hn = 8, Fn = 2048, Kw = 31, Dk = 64;
static constexpr size_t N_OUT  = (size_t)Bsz * Tn * Dn;   // 2,097,152
static constexpr size_t N_POSK = (size_t)Tn * Tn * Dk;    // 67,108,864
static constexpr size_t N_MASK = (size_t)Bsz * Tn * Tn;   // 4,194,304

// ---------------------------------------------------------------------------
// LayerNorm (one 256-thread block per row of D=512), optional fused GLU
// ---------------------------------------------------------------------------
template <int GLU>
__global__ __launch_bounds__(256) void ln_kernel(
    const float* __restrict__ x, const float* __restrict__ g,
    const float* __restrict__ b, float* __restrict__ y,
    const float* __restrict__ pw1w, const float* __restrict__ pw1b) {
  const int row = blockIdx.x;
  const float* xr = x + (size_t)row * Dn;
  float* yr = y + (size_t)row * Dn;
  const int tid = threadIdx.x, wid = tid >> 6, lane = tid & 63;

  __shared__ float red[4];
  __shared__ float bc[2];

  float v0 = xr[tid], v1 = xr[tid + 256];
  float s = v0 + v1;
#pragma unroll
  for (int off = 32; off; off >>= 1) s += __shfl_xor(s, off);
  if (lane == 0) red[wid] = s;
  __syncthreads();
  if (tid == 0) bc[0] = (red[0] + red[1] + red[2] + red[3]) * (1.0f / Dn);
  __syncthreads();
  const float m = bc[0];
  const float d0 = v0 - m, d1 = v1 - m;
  float s2 = d0 * d0 + d1 * d1;
#pragma unroll
  for (int off = 32; off; off >>= 1) s2 += __shfl_xor(s2, off);
  if (lane == 0) red[wid] = s2;
  __syncthreads();
  if (tid == 0)
    bc[1] = rsqrtf((red[0] + red[1] + red[2] + red[3]) * (1.0f / Dn) + 1e-5f);
  __syncthreads();
  const float r = bc[1];

  float o0 = d0 * r * g[tid] + b[tid];
  float o1 = d1 * r * g[tid + 256] + b[tid + 256];
  if (GLU) {
    const float w0 = pw1w[0], w1 = pw1w[1], c0 = pw1b[0], c1 = pw1b[1];
    o0 = (w0 * o0 + c0) * (1.0f / (1.0f + expf(-(w1 * o0 + c1))));
    o1 = (w0 * o1 + c0) * (1.0f / (1.0f + expf(-(w1 * o1 + c1))));
  }
  yr[tid] = o0;
  yr[tid + 256] = o1;
}

// ---------------------------------------------------------------------------
// fp32 tiled GEMM: C(M,N) = epilogue(A(M,K) @ W(K,N) + bias[n])
// MODE 0: relu  1: res+0.5*v  2: v  3: res+v
// ---------------------------------------------------------------------------
template <int MODE>
__global__ __launch_bounds__(256) void gemm_kernel(
    const float* __restrict__ A, const float* __restrict__ W,
    const float* __restrict__ bias, const float* __restrict__ res,
    float* __restrict__ C, int M, int N, int Kdim) {
  __shared__ float As[16][129];
  __shared__ float Bs[16][128];
  const int bm = blockIdx.y * 128, bn = blockIdx.x * 128;
  const int tid = threadIdx.x;
  const int tx = tid & 15, ty = tid >> 4;

  float acc[8][8] = {};

  for (int k0 = 0; k0 < Kdim; k0 += 16) {
#pragma unroll
    for (int i = 0; i < 2; ++i) {
      int idx = tid + i * 256;
      int r = idx >> 2, c4 = idx & 3;
      const float4 av =
          *(const float4*)(A + (size_t)(bm + r) * Kdim + k0 + c4 * 4);
      As[c4 * 4 + 0][r] = av.x;
      As[c4 * 4 + 1][r] = av.y;
      As[c4 * 4 + 2][r] = av.z;
      As[c4 * 4 + 3][r] = av.w;
    }
#pragma unroll
    for (int i = 0; i < 2; ++i) {
      int idx = tid + i * 256;
      int r = idx >> 5, c4 = idx & 31;
      *(float4*)&Bs[r][c4 * 4] =
          *(const float4*)(W + (size_t)(k0 + r) * N + bn + c4 * 4);
    }
    __syncthreads();
#pragma unroll
    for (int kk = 0; kk < 16; ++kk) {
      float a[8], bb[8];
#pragma unroll
      for (int i = 0; i < 4; ++i) {
        a[i] = As[kk][ty * 4 + i];
        a[4 + i] = As[kk][64 + ty * 4 + i];
      }
#pragma unroll
      for (int j = 0; j < 4; ++j) {
        bb[j] = Bs[kk][tx * 4 + j];
        bb[4 + j] = Bs[kk][64 + tx * 4 + j];
      }
#pragma unroll
      for (int i = 0; i < 8; ++i)
#pragma unroll
        for (int j = 0; j < 8; ++j) acc[i][j] += a[i] * bb[j];
    }
    __syncthreads();
  }

#pragma unroll
  for (int i = 0; i < 8; ++i) {
    int m = bm + ((i < 4) ? (ty * 4 + i) : (64 + ty * 4 + (i - 4)));
#pragma unroll
    for (int j = 0; j < 8; ++j) {
      int n = bn + ((j < 4) ? (tx * 4 + j) : (64 + tx * 4 + (j - 4)));
      float v = acc[i][j] + bias[n];
      if (MODE == 0) v = fmaxf(v, 0.0f);
      if (MODE == 1) v = res[(size_t)m * N + n] + 0.5f * v;
      if (MODE == 3) v = res[(size_t)m * N + n] + v;
      C[(size_t)m * N + n] = v;
    }
  }
}

// ---------------------------------------------------------------------------
// bm_kernel: Sc[bh][t][s] = q[b,t,h,:] . pos_k[t,s,:]
// block = (t, s-half of 512); 256 thr; per chunk of 64 s: stage P in LDS,
// q via wave-uniform (scalar-cached) global loads.
// ---------------------------------------------------------------------------
__global__ __launch_bounds__(256) void bm_kernel(
    const float* __restrict__ qb, const float* __restrict__ pk,
    float* __restrict__ Sc) {
  const int t = blockIdx.x;
  const int s0 = blockIdx.y * 512;
  const int tid = threadIdx.x;
  const int grp = tid >> 6;  // wave id -> bh base grp*8 (wave-uniform)
  const int sl = tid & 63;

  __shared__ float Ps[64][65];

  for (int chunk = 0; chunk < 8; ++chunk) {
    const int sbase = s0 + chunk * 64;
    // stage P[64 s][64 d]
#pragma unroll
    for (int i = 0; i < 4; ++i) {
      int flat = tid + i * 256;  // float4 id, 1024 total
      int sr = flat >> 4, d4 = flat & 15;
      const float4 v =
          *(const float4*)(pk + ((size_t)t * Tn + sbase + sr) * Dk + d4 * 4);
      Ps[sr][d4 * 4 + 0] = v.x;
      Ps[sr][d4 * 4 + 1] = v.y;
      Ps[sr][d4 * 4 + 2] = v.z;
      Ps[sr][d4 * 4 + 3] = v.w;
    }
    __syncthreads();

    float acc[8] = {};
#pragma unroll 4
    for (int d4 = 0; d4 < 16; ++d4) {
      const float p0 = Ps[sl][d4 * 4 + 0];
      const float p1 = Ps[sl][d4 * 4 + 1];
      const float p2 = Ps[sl][d4 * 4 + 2];
      const float p3 = Ps[sl][d4 * 4 + 3];
#pragma unroll
      for (int j = 0; j < 8; ++j) {
        const int bh = grp * 8 + j;
        const int bq = bh >> 3, hq = bh & 7;
        const float4 qv = *(const float4*)(
            qb + ((size_t)(bq * Tn + t)) * Dn + hq * 64 + d4 * 4);
        acc[j] += qv.x * p0 + qv.y * p1 + qv.z * p2 + qv.w * p3;
      }
    }
    __syncthreads();
#pragma unroll
    for (int j = 0; j < 8; ++j) {
      const int bh = grp * 8 + j;
      Sc[((size_t)bh * Tn + t) * Tn + sbase + sl] = acc[j];
    }
  }
}

// ---------------------------------------------------------------------------
// qk_kernel: Sc[bh][t][s] = (Sc + Q.K^T) * scale, masked -> -3e38
// NT GEMM, 128x128 tile, BK=16 over K=64, 8x8 per thread.
// ---------------------------------------------------------------------------
__global__ __launch_bounds__(256) void qk_kernel(
    const float* __restrict__ qb, const float* __restrict__ kb,
    const int* __restrict__ mask, float* __restrict__ Sc) {
  const int bh = blockIdx.z;
  const int b = bh >> 3, h = bh & 7;
  const int bm = blockIdx.y * 128;  // t
  const int bn = blockIdx.x * 128;  // s
  const int tid = threadIdx.x;
  const int tx = tid & 15, ty = tid >> 4;

  __shared__ float As[16][129];
  __shared__ float Bs[16][129];

  const float* qbase = qb + (size_t)b * Tn * Dn + h * 64;
  const float* kbase = kb + (size_t)b * Tn * Dn + h * 64;

  float acc[8][8] = {};

  for (int k0 = 0; k0 < Dk; k0 += 16) {
#pragma unroll
    for (int i = 0; i < 2; ++i) {
      int idx = tid + i * 256;
      int r = idx >> 2, c4 = idx & 3;
      const float4 av =
          *(const float4*)(qbase + (size_t)(bm + r) * Dn + k0 + c4 * 4);
      As[c4 * 4 + 0][r] = av.x;
      As[c4 * 4 + 1][r] = av.y;
      As[c4 * 4 + 2][r] = av.z;
      As[c4 * 4 + 3][r] = av.w;
      const float4 bv =
          *(const float4*)(kbase + (size_t)(bn + r) * Dn + k0 + c4 * 4);
      Bs[c4 * 4 + 0][r] = bv.x;
      Bs[c4 * 4 + 1][r] = bv.y;
      Bs[c4 * 4 + 2][r] = bv.z;
      Bs[c4 * 4 + 3][r] = bv.w;
    }
    __syncthreads();
#pragma unroll
    for (int kk = 0; kk < 16; ++kk) {
      float a[8], bb[8];
#pragma unroll
      for (int i = 0; i < 4; ++i) {
        a[i] = As[kk][ty * 4 + i];
        a[4 + i] = As[kk][64 + ty * 4 + i];
        bb[i] = Bs[kk][tx * 4 + i];
        bb[4 + i] = Bs[kk][64 + tx * 4 + i];
      }
#pragma unroll
      for (int i = 0; i < 8; ++i)
#pragma unroll
        for (int j = 0; j < 8; ++j) acc[i][j] += a[i] * bb[j];
    }
    __syncthreads();
  }

  const float scale = 0.125f;  // 1/sqrt(64)
#pragma unroll
  for (int i = 0; i < 8; ++i) {
    int m = bm + ((i < 4) ? (ty * 4 + i) : (64 + ty * 4 + (i - 4)));
#pragma unroll
    for (int j = 0; j < 8; ++j) {
      int n = bn + ((j < 4) ? (tx * 4 + j) : (64 + tx * 4 + (j - 4)));
      size_t off = ((size_t)bh * Tn + m) * Tn + n;
      float v = (Sc[off] + acc[i][j]) * scale;
      if (mask[((size_t)b * Tn + m) * Tn + n] == 0) v = -3.0e38f;
      Sc[off] = v;
    }
  }
}

// ---------------------------------------------------------------------------
// softmax_kernel: in-place row softmax over Tn=1024; block per row.
// ---------------------------------------------------------------------------
__global__ __launch_bounds__(256) void softmax_kernel(float* __restrict__ Sc) {
  float* r = Sc + (size_t)blockIdx.x * Tn;
  const int tid = threadIdx.x, wid = tid >> 6, lane = tid & 63;
  __shared__ float red[4];
  __shared__ float bcv[2];

  float4 v = ((const float4*)r)[tid];
  float mx = fmaxf(fmaxf(v.x, v.y), fmaxf(v.z, v.w));
#pragma unroll
  for (int off = 32; off; off >>= 1) mx = fmaxf(mx, __shfl_xor(mx, off));
  if (lane == 0) red[wid] = mx;
  __syncthreads();
  if (tid == 0) bcv[0] = fmaxf(fmaxf(red[0], red[1]), fmaxf(red[2], red[3]));
  __syncthreads();
  mx = bcv[0];

  v.x = __expf(v.x - mx);
  v.y = __expf(v.y - mx);
  v.z = __expf(v.z - mx);
  v.w = __expf(v.w - mx);
  float ss = v.x + v.y + v.z + v.w;
#pragma unroll
  for (int off = 32; off; off >>= 1) ss += __shfl_xor(ss, off);
  if (lane == 0) red[wid] = ss;
  __syncthreads();
  if (tid == 0)
    bcv[1] = 1.0f / fmaxf(red[0] + red[1] + red[2] + red[3], 1e-30f);
  __syncthreads();
  const float inv = bcv[1];
  v.x *= inv;
  v.y *= inv;
  v.z *= inv;
  v.w *= inv;
  ((float4*)r)[tid] = v;
}

// ---------------------------------------------------------------------------
// pv_kernel: ctx[b,t,h*64+d] = sum_s P[bh][t][s] * v[b,s,h*64+d]
// block = (t-tile 64, bh); K-loop over s in chunks of 32; 4x4 per thread.
// ---------------------------------------------------------------------------
__global__ __launch_bounds__(256) void pv_kernel(
    const float* __restrict__ Sc, const float* __restrict__ vb,
    float* __restrict__ ctx) {
  const int bh = blockIdx.y;
  const int b = bh >> 3, h = bh & 7;
  const int t0 = blockIdx.x * 64;
  const int tid = threadIdx.x;
  const int tx = tid & 15, ty = tid >> 4;

  __shared__ float Ps[64][33];
  __shared__ float Vs[32][65];

  float acc[4][4] = {};

  for (int s0 = 0; s0 < Tn; s0 += 32) {
    // stage P: 64 t x 32 s
#pragma unroll
    for (int i = 0; i < 2; ++i) {
      int flat = tid + i * 256;  // float4 id, 512 total
      int rr = flat >> 3, c4 = flat & 7;
      const float4 p4 =
          *(const float4*)(Sc + ((size_t)bh * Tn + t0 + rr) * Tn + s0 + c4 * 4);
      Ps[rr][c4 * 4 + 0] = p4.x;
      Ps[rr][c4 * 4 + 1] = p4.y;
      Ps[rr][c4 * 4 + 2] = p4.z;
      Ps[rr][c4 * 4 + 3] = p4.w;
    }
    // stage V: 32 s x 64 d
#pragma unroll
    for (int i = 0; i < 2; ++i) {
      int flat = tid + i * 256;
      int rr = flat >> 4, c4 = flat & 15;
      const float4 v4 = *(const float4*)(
          vb + ((size_t)(b * Tn + s0 + rr)) * Dn + h * 64 + c4 * 4);
      Vs[rr][c4 * 4 + 0] = v4.x;
      Vs[rr][c4 * 4 + 1] = v4.y;
      Vs[rr][c4 * 4 + 2] = v4.z;
      Vs[rr][c4 * 4 + 3] = v4.w;
    }
    __syncthreads();
#pragma unroll 8
    for (int ss = 0; ss < 32; ++ss) {
      float pv[4], vv[4];
#pragma unroll
      for (int i = 0; i < 4; ++i) pv[i] = Ps[ty * 4 + i][ss];
#pragma unroll
      for (int j = 0; j < 4; ++j) vv[j] = Vs[ss][tx * 4 + j];
#pragma unroll
      for (int i = 0; i < 4; ++i)
#pragma unroll
        for (int j = 0; j < 4; ++j) acc[i][j] += pv[i] * vv[j];
    }
    __syncthreads();
  }

#pragma unroll
  for (int i = 0; i < 4; ++i) {
    const int t = t0 + ty * 4 + i;
#pragma unroll
    for (int j = 0; j < 4; ++j) {
      const int d = tx * 4 + j;
      ctx[((size_t)(b * Tn + t)) * Dn + h * 64 + d] = acc[i][j];
    }
  }
}

// ---------------------------------------------------------------------------
// Depthwise conv1d (K=31, pad 15) + ReLU + pointwise2 + residual
// ---------------------------------------------------------------------------
__global__ __launch_bounds__(256) void conv_kernel(
    const float* __restrict__ y, const float* __restrict__ dw,
    const float* __restrict__ dwb, const float* __restrict__ pw2w,
    const float* __restrict__ pw2b, float* __restrict__ x) {
  const int bt = blockIdx.x;
  const int b = bt >> 10, t = bt & (Tn - 1);
  const int tid = threadIdx.x;
  const float w2 = pw2w[0], c2 = pw2b[0];

  for (int dd = tid; dd < Dn; dd += 256) {
    float acc = dwb[dd];
#pragma unroll
    for (int k = 0; k < Kw; ++k) {
      int s = t + k - 15;
      if (s >= 0 && s < Tn)
        acc += dw[dd * Kw + k] * y[((size_t)b * Tn + s) * Dn + dd];
    }
    acc = fmaxf(acc, 0.0f);
    size_t idx = ((size_t)b * Tn + t) * Dn + dd;
    x[idx] = x[idx] + w2 * acc + c2;
  }
}

// ---------------------------------------------------------------------------
// int32 -> float32 conversion (mask passthrough)
// ---------------------------------------------------------------------------
__global__ __launch_bounds__(256) void i2f_kernel(const int* __restrict__ in,
                                                  float* __restrict__ out,
                                                  size_t n4) {
  size_t i = (size_t)blockIdx.x * 256 + threadIdx.x;
  if (i < n4) {
    const int4 v = ((const int4*)in)[i];
    float4 f;
    f.x = (float)v.x;
    f.y = (float)v.y;
    f.z = (float)v.z;
    f.w = (float)v.w;
    ((float4*)out)[i] = f;
  }
}

// ---------------------------------------------------------------------------
extern "C" void kernel_launch(void* const* d_in, const int* in_sizes, int n_in,
                              void* d_out, int out_size, void* d_ws,
                              size_t ws_size, hipStream_t stream) {
  const float* x = (const float*)d_in[0];
  const float* pos_k = (const float*)d_in[1];
  const int* mask = (const int*)d_in[2];
  const float* fi_g = (const float*)d_in[3];
  const float* fi_b = (const float*)d_in[4];
  const float* fi_w1 = (const float*)d_in[5];
  const float* fi_b1 = (const float*)d_in[6];
  const float* fi_w2 = (const float*)d_in[7];
  const float* fi_b2 = (const float*)d_in[8];
  const float* at_g = (const float*)d_in[9];
  const float* at_b = (const float*)d_in[10];
  const float* wq = (const float*)d_in[11];
  const float* bq = (const float*)d_in[12];
  const float* wk = (const float*)d_in[13];
  const float* bk = (const float*)d_in[14];
  const float* wv = (const float*)d_in[15];
  const float* bv = (const float*)d_in[16];
  const float* wo = (const float*)d_in[17];
  const float* bo = (const float*)d_in[18];
  const float* cv_g = (const float*)d_in[19];
  const float* cv_b = (const float*)d_in[20];
  const float* pw1w = (const float*)d_in[21];
  const float* pw1b = (const float*)d_in[22];
  const float* dww = (const float*)d_in[23];
  const float* dwb = (const float*)d_in[24];
  const float* pw2w = (const float*)d_in[25];
  const float* pw2b = (const float*)d_in[26];
  const float* fo_g = (const float*)d_in[27];
  const float* fo_b = (const float*)d_in[28];
  const float* fo_w1 = (const float*)d_in[29];
  const float* fo_b1 = (const float*)d_in[30];
  const float* fo_w2 = (const float*)d_in[31];
  const float* fo_b2 = (const float*)d_in[32];
  const float* fl_g = (const float*)d_in[33];
  const float* fl_b = (const float*)d_in[34];

  float* out = (float*)d_out;
  float* ws = (float*)d_ws;

  // workspace layout (floats): xcur[2M] | y[2M] | U[8M]
  float* xcur = ws;
  float* y = ws + N_OUT;
  float* U = ws + 2 * N_OUT;
  float* hbuf = U;
  float* qbuf = U;
  float* kbuf = U + N_OUT;
  float* vbuf = U + 2 * N_OUT;
  float* ctx = U + 3 * N_OUT;

  // scores scratch (B*H*T*T fp32 = 134 MB) in the pos_k passthrough region
  // of d_out (268 MB), overwritten by the passthrough copy at the end.
  float* Sc = out + N_OUT;

  const int M = Bsz * Tn;  // 4096
  const dim3 blk256(256);
  const dim3 grid_rows(M);
  const dim3 gF(Fn / 128, M / 128);
  const dim3 gD(Dn / 128, M / 128);

  hipMemcpyAsync(xcur, x, N_OUT * sizeof(float), hipMemcpyDeviceToDevice,
                 stream);

  // macaron FFN-in
  ln_kernel<0><<<grid_rows, blk256, 0, stream>>>(xcur, fi_g, fi_b, y, nullptr,
                                                 nullptr);
  gemm_kernel<0><<<gF, blk256, 0, stream>>>(y, fi_w1, fi_b1, nullptr, hbuf, M,
                                            Fn, Dn);
  gemm_kernel<1><<<gD, blk256, 0, stream>>>(hbuf, fi_w2, fi_b2, xcur, xcur, M,
                                            Dn, Fn);

  // attention
  ln_kernel<0><<<grid_rows, blk256, 0, stream>>>(xcur, at_g, at_b, y, nullptr,
                                                 nullptr);
  gemm_kernel<2><<<gD, blk256, 0, stream>>>(y, wq, bq, nullptr, qbuf, M, Dn,
                                            Dn);
  gemm_kernel<2><<<gD, blk256, 0, stream>>>(y, wk, bk, nullptr, kbuf, M, Dn,
                                            Dn);
  gemm_kernel<2><<<gD, blk256, 0, stream>>>(y, wv, bv, nullptr, vbuf, M, Dn,
                                            Dn);

  bm_kernel<<<dim3(Tn, 2), blk256, 0, stream>>>(qbuf, pos_k, Sc);
  qk_kernel<<<dim3(8, 8, 32), blk256, 0, stream>>>(qbuf, kbuf, mask, Sc);
  softmax_kernel<<<dim3(32 * Tn), blk256, 0, stream>>>(Sc);
  pv_kernel<<<dim3(16, 32), blk256, 0, stream>>>(Sc, vbuf, ctx);

  gemm_kernel<3><<<gD, blk256, 0, stream>>>(ctx, wo, bo, xcur, xcur, M, Dn,
                                            Dn);

  // conv module
  ln_kernel<1><<<grid_rows, blk256, 0, stream>>>(xcur, cv_g, cv_b, y, pw1w,
                                                 pw1b);
  conv_kernel<<<grid_rows, blk256, 0, stream>>>(y, dww, dwb, pw2w, pw2b, xcur);

  // macaron FFN-out
  ln_kernel<0><<<grid_rows, blk256, 0, stream>>>(xcur, fo_g, fo_b, y, nullptr,
                                                 nullptr);
  gemm_kernel<0><<<gF, blk256, 0, stream>>>(y, fo_w1, fo_b1, nullptr, hbuf, M,
                                            Fn, Dn);
  gemm_kernel<1><<<gD, blk256, 0, stream>>>(hbuf, fo_w2, fo_b2, xcur, xcur, M,
                                            Dn, Fn);

  // final LN -> d_out[0]
  ln_kernel<0><<<grid_rows, blk256, 0, stream>>>(xcur, fl_g, fl_b, out,
                                                 nullptr, nullptr);

  // passthrough outputs (AFTER Sc scratch use): pos_k copy, mask convert
  hipMemcpyAsync(out + N_OUT, pos_k, N_POSK * sizeof(float),
                 hipMemcpyDeviceToDevice, stream);
  i2f_kernel<<<dim3((N_MASK / 4 + 255) / 256), blk256, 0, stream>>>(
      mask, out + N_OUT + N_POSK, N_MASK / 4);
}

// Round 4
// 849.055 us; speedup vs baseline: 5.7448x; 2.2133x over previous
//
#include <hip/hip_runtime.h>
#include <math.h>

static constexpr int Bsz = 4, Tn = 1024, Dn = 512, Hn = 8, Fn = 2048, Kw = 31, Dk = 64;
static constexpr size_t N_OUT  = (size_t)Bsz * Tn * Dn;   // 2,097,152
static constexpr size_t N_POSK = (size_t)Tn * Tn * Dk;    // 67,108,864
static constexpr size_t N_MASK = (size_t)Bsz * Tn * Tn;   // 4,194,304

typedef __attribute__((ext_vector_type(8))) short bhalf8;  // 8 bf16 (4 VGPR)
typedef __attribute__((ext_vector_type(4))) float f4;      // MFMA C/D

__device__ __forceinline__ ushort f2b(float f) {
  uint b = __float_as_uint(f);
  uint r = (b + 0x7FFFu + ((b >> 16) & 1u)) >> 16;
  return (ushort)r;
}

// ---------------------------------------------------------------------------
// LayerNorm; BF=1 -> bf16 output (GEMM A operand), BF=0 -> fp32 output.
// GLU=1 applies (w0*y+c0)*sigmoid(w1*y+c1) (fp32 out only).
// ---------------------------------------------------------------------------
template <int GLU, int BF>
__global__ __launch_bounds__(256) void ln_kernel(
    const float* __restrict__ x, const float* __restrict__ g,
    const float* __restrict__ b, float* __restrict__ yf,
    ushort* __restrict__ yb, const float* __restrict__ pw1w,
    const float* __restrict__ pw1b) {
  const int row = blockIdx.x;
  const float* xr = x + (size_t)row * Dn;
  const int tid = threadIdx.x, wid = tid >> 6, lane = tid & 63;

  __shared__ float red[4];
  __shared__ float bc[2];

  float v0 = xr[tid], v1 = xr[tid + 256];
  float s = v0 + v1;
#pragma unroll
  for (int off = 32; off; off >>= 1) s += __shfl_xor(s, off);
  if (lane == 0) red[wid] = s;
  __syncthreads();
  if (tid == 0) bc[0] = (red[0] + red[1] + red[2] + red[3]) * (1.0f / Dn);
  __syncthreads();
  const float m = bc[0];
  const float d0 = v0 - m, d1 = v1 - m;
  float s2 = d0 * d0 + d1 * d1;
#pragma unroll
  for (int off = 32; off; off >>= 1) s2 += __shfl_xor(s2, off);
  if (lane == 0) red[wid] = s2;
  __syncthreads();
  if (tid == 0)
    bc[1] = rsqrtf((red[0] + red[1] + red[2] + red[3]) * (1.0f / Dn) + 1e-5f);
  __syncthreads();
  const float r = bc[1];

  float o0 = d0 * r * g[tid] + b[tid];
  float o1 = d1 * r * g[tid + 256] + b[tid + 256];
  if (GLU) {
    const float w0 = pw1w[0], w1 = pw1w[1], c0 = pw1b[0], c1 = pw1b[1];
    o0 = (w0 * o0 + c0) * (1.0f / (1.0f + expf(-(w1 * o0 + c1))));
    o1 = (w0 * o1 + c0) * (1.0f / (1.0f + expf(-(w1 * o1 + c1))));
  }
  if (BF) {
    yb[(size_t)row * Dn + tid] = f2b(o0);
    yb[(size_t)row * Dn + tid + 256] = f2b(o1);
  } else {
    yf[(size_t)row * Dn + tid] = o0;
    yf[(size_t)row * Dn + tid + 256] = o1;
  }
}

// ---------------------------------------------------------------------------
// Weight convert+transpose: W (K x N fp32, row-major) -> Wt (N x K bf16)
// ---------------------------------------------------------------------------
__global__ __launch_bounds__(256) void wcvt_kernel(const float* __restrict__ W,
                                                   ushort* __restrict__ Wt,
                                                   int K, int N) {
  __shared__ float tile[32][33];
  const int n0 = blockIdx.x * 32, k0 = blockIdx.y * 32;
  const int tx = threadIdx.x & 31, ty = threadIdx.x >> 5;  // ty 0..7
#pragma unroll
  for (int i = 0; i < 4; ++i) {
    int k = ty + i * 8;
    tile[k][tx] = W[(size_t)(k0 + k) * N + n0 + tx];
  }
  __syncthreads();
#pragma unroll
  for (int i = 0; i < 4; ++i) {
    int r = ty + i * 8;  // local n
    Wt[(size_t)(n0 + r) * K + k0 + tx] = f2b(tile[tx][r]);
  }
}

// ---------------------------------------------------------------------------
// bf16 MFMA GEMM (NT): C(M,N) = epi(A(M,K)bf16 @ Wt(N,K)bf16^T + bias)
// 128x128 tile, BK=64, 4 waves (2x2), each wave 64x64 (4x4 frags 16x16x32).
// MODE 0: relu -> bf16 Cb only
// MODE 1: C = res + 0.5*v (fp32)
// MODE 2: C = v (fp32); WBF also writes bf16 Cb
// MODE 3: C = res + v (fp32)
// ---------------------------------------------------------------------------
template <int MODE, int WBF>
__global__ __launch_bounds__(256) void mgemm_kernel(
    const ushort* __restrict__ A, const ushort* __restrict__ Bt,
    const float* __restrict__ bias, const float* __restrict__ res,
    float* __restrict__ C, ushort* __restrict__ Cb, int M, int N, int K) {
  __shared__ ushort As[128 * 64];
  __shared__ ushort Bs[128 * 64];
  const int bm = blockIdx.y * 128, bn = blockIdx.x * 128;
  const int tid = threadIdx.x;
  const int wid = tid >> 6, l = tid & 63;
  const int wm = wid >> 1, wn = wid & 1;
  const int l16 = l & 15, lhi = l >> 4;

  f4 acc[4][4] = {};

  for (int k0 = 0; k0 < K; k0 += 64) {
    // stage A,B tiles: 1024 slots of 8 bf16 each per tile, 4 per thread
#pragma unroll
    for (int i = 0; i < 4; ++i) {
      int slot = tid + i * 256;
      int row = slot >> 3, c8 = slot & 7;
      *(uint4*)&As[row * 64 + c8 * 8] =
          *(const uint4*)(A + (size_t)(bm + row) * K + k0 + c8 * 8);
      *(uint4*)&Bs[row * 64 + c8 * 8] =
          *(const uint4*)(Bt + (size_t)(bn + row) * K + k0 + c8 * 8);
    }
    __syncthreads();
#pragma unroll
    for (int ks = 0; ks < 2; ++ks) {
      bhalf8 a[4], b[4];
#pragma unroll
      for (int mi = 0; mi < 4; ++mi)
        a[mi] = *(const bhalf8*)&As[(wm * 64 + mi * 16 + l16) * 64 + ks * 32 +
                                    lhi * 8];
#pragma unroll
      for (int ni = 0; ni < 4; ++ni)
        b[ni] = *(const bhalf8*)&Bs[(wn * 64 + ni * 16 + l16) * 64 + ks * 32 +
                                    lhi * 8];
#pragma unroll
      for (int mi = 0; mi < 4; ++mi)
#pragma unroll
        for (int ni = 0; ni < 4; ++ni)
          acc[mi][ni] = __builtin_amdgcn_mfma_f32_16x16x32_bf16(
              a[mi], b[ni], acc[mi][ni], 0, 0, 0);
    }
    __syncthreads();
  }

  // epilogue: C/D layout col=lane&15, row=(lane>>4)*4+reg  [m89-verified]
#pragma unroll
  for (int mi = 0; mi < 4; ++mi) {
#pragma unroll
    for (int ni = 0; ni < 4; ++ni) {
      const int col = bn + wn * 64 + ni * 16 + l16;
      const float bv = bias[col];
#pragma unroll
      for (int r = 0; r < 4; ++r) {
        const int row = bm + wm * 64 + mi * 16 + lhi * 4 + r;
        float v = acc[mi][ni][r] + bv;
        const size_t off = (size_t)row * N + col;
        if (MODE == 0) {
          Cb[off] = f2b(fmaxf(v, 0.0f));
        } else {
          if (MODE == 1) v = res[off] + 0.5f * v;
          if (MODE == 3) v = res[off] + v;
          C[off] = v;
          if (WBF) Cb[off] = f2b(v);
        }
      }
    }
  }
}

// ---------------------------------------------------------------------------
// bmm_kernel: Sc[bh][t][s] = q[b,t,h,:] . pos_k[t,s,:] via MFMA.
// block = (s-quarter, t); stage Q(32x64) + P(256x64, fp32->bf16) in LDS.
// Wave w covers s-tile of 64; M=32 (2 m-frags), 4 n-frags, 2 k-steps.
// ---------------------------------------------------------------------------
__global__ __launch_bounds__(256) void bmm_kernel(const ushort* __restrict__ qbf,
                                                  const float* __restrict__ pk,
                                                  float* __restrict__ Sc) {
  const int s0 = blockIdx.x * 256;
  const int t = blockIdx.y;
  const int tid = threadIdx.x, wid = tid >> 6, l = tid & 63;
  const int l16 = l & 15, lhi = l >> 4;

  __shared__ ushort Qs[32 * 64];   // 4 KB
  __shared__ ushort Ps[256 * 64];  // 32 KB

  {  // stage Q: 256 slots of 8 bf16
    int row = tid >> 3, c8 = tid & 7;
    int bq = row >> 3, hq = row & 7;
    *(uint4*)&Qs[row * 64 + c8 * 8] =
        *(const uint4*)(qbf + ((size_t)(bq * Tn + t)) * Dn + hq * 64 + c8 * 8);
  }
#pragma unroll
  for (int i = 0; i < 16; ++i) {  // stage P: 4096 float4 slots
    int slot = tid + i * 256;
    int sr = slot >> 4, c4 = slot & 15;
    const float4 p =
        *(const float4*)(pk + ((size_t)t * Tn + s0 + sr) * Dk + c4 * 4);
    ushort4 u;
    u.x = f2b(p.x);
    u.y = f2b(p.y);
    u.z = f2b(p.z);
    u.w = f2b(p.w);
    *(ushort4*)&Ps[sr * 64 + c4 * 4] = u;
  }
  __syncthreads();

  f4 acc[2][4] = {};
#pragma unroll
  for (int ks = 0; ks < 2; ++ks) {
    bhalf8 a[2], b[4];
#pragma unroll
    for (int mi = 0; mi < 2; ++mi)
      a[mi] = *(const bhalf8*)&Qs[(mi * 16 + l16) * 64 + ks * 32 + lhi * 8];
#pragma unroll
    for (int ni = 0; ni < 4; ++ni)
      b[ni] = *(const bhalf8*)&Ps[(wid * 64 + ni * 16 + l16) * 64 + ks * 32 +
                                  lhi * 8];
#pragma unroll
    for (int mi = 0; mi < 2; ++mi)
#pragma unroll
      for (int ni = 0; ni < 4; ++ni)
        acc[mi][ni] = __builtin_amdgcn_mfma_f32_16x16x32_bf16(
            a[mi], b[ni], acc[mi][ni], 0, 0, 0);
  }

#pragma unroll
  for (int mi = 0; mi < 2; ++mi)
#pragma unroll
    for (int ni = 0; ni < 4; ++ni)
#pragma unroll
      for (int r = 0; r < 4; ++r) {
        const int bh = mi * 16 + lhi * 4 + r;
        const int s = s0 + wid * 64 + ni * 16 + l16;
        Sc[((size_t)bh * Tn + t) * Tn + s] = acc[mi][ni][r];
      }
}

// ---------------------------------------------------------------------------
// qk_kernel: Sc[bh][t][s] = (Sc + Q.K^T) * scale, masked -> -3e38 (fp32 SIMT)
// ---------------------------------------------------------------------------
__global__ __launch_bounds__(256) void qk_kernel(
    const float* __restrict__ qb, const float* __restrict__ kb,
    const int* __restrict__ mask, float* __restrict__ Sc) {
  const int bh = blockIdx.z;
  const int b = bh >> 3, h = bh & 7;
  const int bm = blockIdx.y * 128;  // t
  const int bn = blockIdx.x * 128;  // s
  const int tid = threadIdx.x;
  const int tx = tid & 15, ty = tid >> 4;

  __shared__ float As[16][129];
  __shared__ float Bs[16][129];

  const float* qbase = qb + (size_t)b * Tn * Dn + h * 64;
  const float* kbase = kb + (size_t)b * Tn * Dn + h * 64;

  float acc[8][8] = {};

  for (int k0 = 0; k0 < Dk; k0 += 16) {
#pragma unroll
    for (int i = 0; i < 2; ++i) {
      int idx = tid + i * 256;
      int r = idx >> 2, c4 = idx & 3;
      const float4 av =
          *(const float4*)(qbase + (size_t)(bm + r) * Dn + k0 + c4 * 4);
      As[c4 * 4 + 0][r] = av.x;
      As[c4 * 4 + 1][r] = av.y;
      As[c4 * 4 + 2][r] = av.z;
      As[c4 * 4 + 3][r] = av.w;
      const float4 bv =
          *(const float4*)(kbase + (size_t)(bn + r) * Dn + k0 + c4 * 4);
      Bs[c4 * 4 + 0][r] = bv.x;
      Bs[c4 * 4 + 1][r] = bv.y;
      Bs[c4 * 4 + 2][r] = bv.z;
      Bs[c4 * 4 + 3][r] = bv.w;
    }
    __syncthreads();
#pragma unroll
    for (int kk = 0; kk < 16; ++kk) {
      float a[8], bb[8];
#pragma unroll
      for (int i = 0; i < 4; ++i) {
        a[i] = As[kk][ty * 4 + i];
        a[4 + i] = As[kk][64 + ty * 4 + i];
        bb[i] = Bs[kk][tx * 4 + i];
        bb[4 + i] = Bs[kk][64 + tx * 4 + i];
      }
#pragma unroll
      for (int i = 0; i < 8; ++i)
#pragma unroll
        for (int j = 0; j < 8; ++j) acc[i][j] += a[i] * bb[j];
    }
    __syncthreads();
  }

  const float scale = 0.125f;
#pragma unroll
  for (int i = 0; i < 8; ++i) {
    int m = bm + ((i < 4) ? (ty * 4 + i) : (64 + ty * 4 + (i - 4)));
#pragma unroll
    for (int j = 0; j < 8; ++j) {
      int n = bn + ((j < 4) ? (tx * 4 + j) : (64 + tx * 4 + (j - 4)));
      size_t off = ((size_t)bh * Tn + m) * Tn + n;
      float v = (Sc[off] + acc[i][j]) * scale;
      if (mask[((size_t)b * Tn + m) * Tn + n] == 0) v = -3.0e38f;
      Sc[off] = v;
    }
  }
}

// ---------------------------------------------------------------------------
// softmax_kernel: in-place row softmax over Tn=1024; block per row.
// ---------------------------------------------------------------------------
__global__ __launch_bounds__(256) void softmax_kernel(float* __restrict__ Sc) {
  float* r = Sc + (size_t)blockIdx.x * Tn;
  const int tid = threadIdx.x, wid = tid >> 6, lane = tid & 63;
  __shared__ float red[4];
  __shared__ float bcv[2];

  float4 v = ((const float4*)r)[tid];
  float mx = fmaxf(fmaxf(v.x, v.y), fmaxf(v.z, v.w));
#pragma unroll
  for (int off = 32; off; off >>= 1) mx = fmaxf(mx, __shfl_xor(mx, off));
  if (lane == 0) red[wid] = mx;
  __syncthreads();
  if (tid == 0) bcv[0] = fmaxf(fmaxf(red[0], red[1]), fmaxf(red[2], red[3]));
  __syncthreads();
  mx = bcv[0];

  v.x = __expf(v.x - mx);
  v.y = __expf(v.y - mx);
  v.z = __expf(v.z - mx);
  v.w = __expf(v.w - mx);
  float ss = v.x + v.y + v.z + v.w;
#pragma unroll
  for (int off = 32; off; off >>= 1) ss += __shfl_xor(ss, off);
  if (lane == 0) red[wid] = ss;
  __syncthreads();
  if (tid == 0)
    bcv[1] = 1.0f / fmaxf(red[0] + red[1] + red[2] + red[3], 1e-30f);
  __syncthreads();
  const float inv = bcv[1];
  v.x *= inv;
  v.y *= inv;
  v.z *= inv;
  v.w *= inv;
  ((float4*)r)[tid] = v;
}

// ---------------------------------------------------------------------------
// pv_kernel: ctxb[b,t,h*64+d] = bf16( sum_s P[bh][t][s] * v[b,s,h*64+d] )
// ---------------------------------------------------------------------------
__global__ __launch_bounds__(256) void pv_kernel(
    const float* __restrict__ Sc, const float* __restrict__ vb,
    ushort* __restrict__ ctxb) {
  const int bh = blockIdx.y;
  const int b = bh >> 3, h = bh & 7;
  const int t0 = blockIdx.x * 64;
  const int tid = threadIdx.x;
  const int tx = tid & 15, ty = tid >> 4;

  __shared__ float Ps[64][33];
  __shared__ float Vs[32][65];

  float acc[4][4] = {};

  for (int s0 = 0; s0 < Tn; s0 += 32) {
#pragma unroll
    for (int i = 0; i < 2; ++i) {
      int flat = tid + i * 256;
      int rr = flat >> 3, c4 = flat & 7;
      const float4 p4 =
          *(const float4*)(Sc + ((size_t)bh * Tn + t0 + rr) * Tn + s0 + c4 * 4);
      Ps[rr][c4 * 4 + 0] = p4.x;
      Ps[rr][c4 * 4 + 1] = p4.y;
      Ps[rr][c4 * 4 + 2] = p4.z;
      Ps[rr][c4 * 4 + 3] = p4.w;
    }
#pragma unroll
    for (int i = 0; i < 2; ++i) {
      int flat = tid + i * 256;
      int rr = flat >> 4, c4 = flat & 15;
      const float4 v4 = *(const float4*)(
          vb + ((size_t)(b * Tn + s0 + rr)) * Dn + h * 64 + c4 * 4);
      Vs[rr][c4 * 4 + 0] = v4.x;
      Vs[rr][c4 * 4 + 1] = v4.y;
      Vs[rr][c4 * 4 + 2] = v4.z;
      Vs[rr][c4 * 4 + 3] = v4.w;
    }
    __syncthreads();
#pragma unroll 8
    for (int ss = 0; ss < 32; ++ss) {
      float pv[4], vv[4];
#pragma unroll
      for (int i = 0; i < 4; ++i) pv[i] = Ps[ty * 4 + i][ss];
#pragma unroll
      for (int j = 0; j < 4; ++j) vv[j] = Vs[ss][tx * 4 + j];
#pragma unroll
      for (int i = 0; i < 4; ++i)
#pragma unroll
        for (int j = 0; j < 4; ++j) acc[i][j] += pv[i] * vv[j];
    }
    __syncthreads();
  }

#pragma unroll
  for (int i = 0; i < 4; ++i) {
    const int t = t0 + ty * 4 + i;
#pragma unroll
    for (int j = 0; j < 4; ++j) {
      const int d = tx * 4 + j;
      ctxb[((size_t)(b * Tn + t)) * Dn + h * 64 + d] = f2b(acc[i][j]);
    }
  }
}

// ---------------------------------------------------------------------------
// Depthwise conv1d (K=31, pad 15) + ReLU + pointwise2 + residual
// ---------------------------------------------------------------------------
__global__ __launch_bounds__(256) void conv_kernel(
    const float* __restrict__ y, const float* __restrict__ dw,
    const float* __restrict__ dwb, const float* __restrict__ pw2w,
    const float* __restrict__ pw2b, float* __restrict__ x) {
  const int bt = blockIdx.x;
  const int b = bt >> 10, t = bt & (Tn - 1);
  const int tid = threadIdx.x;
  const float w2 = pw2w[0], c2 = pw2b[0];

  for (int dd = tid; dd < Dn; dd += 256) {
    float acc = dwb[dd];
#pragma unroll
    for (int k = 0; k < Kw; ++k) {
      int s = t + k - 15;
      if (s >= 0 && s < Tn)
        acc += dw[dd * Kw + k] * y[((size_t)b * Tn + s) * Dn + dd];
    }
    acc = fmaxf(acc, 0.0f);
    size_t idx = ((size_t)b * Tn + t) * Dn + dd;
    x[idx] = x[idx] + w2 * acc + c2;
  }
}

// ---------------------------------------------------------------------------
// int32 -> float32 conversion (mask passthrough)
// ---------------------------------------------------------------------------
__global__ __launch_bounds__(256) void i2f_kernel(const int* __restrict__ in,
                                                  float* __restrict__ out,
                                                  size_t n4) {
  size_t i = (size_t)blockIdx.x * 256 + threadIdx.x;
  if (i < n4) {
    const int4 v = ((const int4*)in)[i];
    float4 f;
    f.x = (float)v.x;
    f.y = (float)v.y;
    f.z = (float)v.z;
    f.w = (float)v.w;
    ((float4*)out)[i] = f;
  }
}

// ---------------------------------------------------------------------------
extern "C" void kernel_launch(void* const* d_in, const int* in_sizes, int n_in,
                              void* d_out, int out_size, void* d_ws,
                              size_t ws_size, hipStream_t stream) {
  const float* x = (const float*)d_in[0];
  const float* pos_k = (const float*)d_in[1];
  const int* mask = (const int*)d_in[2];
  const float* fi_g = (const float*)d_in[3];
  const float* fi_b = (const float*)d_in[4];
  const float* fi_w1 = (const float*)d_in[5];
  const float* fi_b1 = (const float*)d_in[6];
  const float* fi_w2 = (const float*)d_in[7];
  const float* fi_b2 = (const float*)d_in[8];
  const float* at_g = (const float*)d_in[9];
  const float* at_b = (const float*)d_in[10];
  const float* wq = (const float*)d_in[11];
  const float* bq = (const float*)d_in[12];
  const float* wk = (const float*)d_in[13];
  const float* bk = (const float*)d_in[14];
  const float* wv = (const float*)d_in[15];
  const float* bv = (const float*)d_in[16];
  const float* wo = (const float*)d_in[17];
  const float* bo = (const float*)d_in[18];
  const float* cv_g = (const float*)d_in[19];
  const float* cv_b = (const float*)d_in[20];
  const float* pw1w = (const float*)d_in[21];
  const float* pw1b = (const float*)d_in[22];
  const float* dww = (const float*)d_in[23];
  const float* dwb = (const float*)d_in[24];
  const float* pw2w = (const float*)d_in[25];
  const float* pw2b = (const float*)d_in[26];
  const float* fo_g = (const float*)d_in[27];
  const float* fo_b = (const float*)d_in[28];
  const float* fo_w1 = (const float*)d_in[29];
  const float* fo_b1 = (const float*)d_in[30];
  const float* fo_w2 = (const float*)d_in[31];
  const float* fo_b2 = (const float*)d_in[32];
  const float* fl_g = (const float*)d_in[33];
  const float* fl_b = (const float*)d_in[34];

  float* out = (float*)d_out;
  float* ws = (float*)d_ws;

  // fp32 workspace: xcur[2M] | y[2M] | qbuf[2M] | kbuf[2M] | vbuf[2M]
  float* xcur = ws;
  float* y = ws + N_OUT;
  float* qbuf = ws + 2 * N_OUT;
  float* kbuf = ws + 3 * N_OUT;
  float* vbuf = ws + 4 * N_OUT;

  // scores scratch (B*H*T*T fp32 = 134 MB): first half of pos_k passthrough
  float* Sc = out + N_OUT;
  // bf16 scratch (~40 MB): second half of pos_k passthrough region
  ushort* p16 = (ushort*)(out + N_OUT + N_POSK / 2);
  ushort* wt_fi1 = p16;            p16 += (size_t)Fn * Dn;   // 2048x512
  ushort* wt_fi2 = p16;            p16 += (size_t)Dn * Fn;   // 512x2048
  ushort* wt_q = p16;              p16 += (size_t)Dn * Dn;
  ushort* wt_k = p16;              p16 += (size_t)Dn * Dn;
  ushort* wt_v = p16;              p16 += (size_t)Dn * Dn;
  ushort* wt_o = p16;              p16 += (size_t)Dn * Dn;
  ushort* wt_fo1 = p16;            p16 += (size_t)Fn * Dn;
  ushort* wt_fo2 = p16;            p16 += (size_t)Dn * Fn;
  ushort* ybf = p16;               p16 += N_OUT;
  ushort* hbf = p16;               p16 += (size_t)Bsz * Tn * Fn;
  ushort* ctxbf = p16;             p16 += N_OUT;
  ushort* qbf = p16;               p16 += N_OUT;

  const int M = Bsz * Tn;  // 4096
  const dim3 blk256(256);
  const dim3 grid_rows(M);
  const dim3 gF(Fn / 128, M / 128);  // (16,32)
  const dim3 gD(Dn / 128, M / 128);  // (4,32)

  hipMemcpyAsync(xcur, x, N_OUT * sizeof(float), hipMemcpyDeviceToDevice,
                 stream);

  // weight conversions (fp32 KxN -> bf16 NxK)
  wcvt_kernel<<<dim3(Fn / 32, Dn / 32), blk256, 0, stream>>>(fi_w1, wt_fi1, Dn, Fn);
  wcvt_kernel<<<dim3(Dn / 32, Fn / 32), blk256, 0, stream>>>(fi_w2, wt_fi2, Fn, Dn);
  wcvt_kernel<<<dim3(Dn / 32, Dn / 32), blk256, 0, stream>>>(wq, wt_q, Dn, Dn);
  wcvt_kernel<<<dim3(Dn / 32, Dn / 32), blk256, 0, stream>>>(wk, wt_k, Dn, Dn);
  wcvt_kernel<<<dim3(Dn / 32, Dn / 32), blk256, 0, stream>>>(wv, wt_v, Dn, Dn);
  wcvt_kernel<<<dim3(Dn / 32, Dn / 32), blk256, 0, stream>>>(wo, wt_o, Dn, Dn);
  wcvt_kernel<<<dim3(Fn / 32, Dn / 32), blk256, 0, stream>>>(fo_w1, wt_fo1, Dn, Fn);
  wcvt_kernel<<<dim3(Dn / 32, Fn / 32), blk256, 0, stream>>>(fo_w2, wt_fo2, Fn, Dn);

  // macaron FFN-in
  ln_kernel<0, 1><<<grid_rows, blk256, 0, stream>>>(xcur, fi_g, fi_b, nullptr,
                                                    ybf, nullptr, nullptr);
  mgemm_kernel<0, 0><<<gF, blk256, 0, stream>>>(ybf, wt_fi1, fi_b1, nullptr,
                                                nullptr, hbf, M, Fn, Dn);
  mgemm_kernel<1, 0><<<gD, blk256, 0, stream>>>(hbf, wt_fi2, fi_b2, xcur, xcur,
                                                nullptr, M, Dn, Fn);

  // attention
  ln_kernel<0, 1><<<grid_rows, blk256, 0, stream>>>(xcur, at_g, at_b, nullptr,
                                                    ybf, nullptr, nullptr);
  mgemm_kernel<2, 1><<<gD, blk256, 0, stream>>>(ybf, wt_q, bq, nullptr, qbuf,
                                                qbf, M, Dn, Dn);
  mgemm_kernel<2, 0><<<gD, blk256, 0, stream>>>(ybf, wt_k, bk, nullptr, kbuf,
                                                nullptr, M, Dn, Dn);
  mgemm_kernel<2, 0><<<gD, blk256, 0, stream>>>(ybf, wt_v, bv, nullptr, vbuf,
                                                nullptr, M, Dn, Dn);

  bmm_kernel<<<dim3(4, Tn), blk256, 0, stream>>>(qbf, pos_k, Sc);
  qk_kernel<<<dim3(8, 8, 32), blk256, 0, stream>>>(qbuf, kbuf, mask, Sc);
  softmax_kernel<<<dim3(32 * Tn), blk256, 0, stream>>>(Sc);
  pv_kernel<<<dim3(16, 32), blk256, 0, stream>>>(Sc, vbuf, ctxbf);

  mgemm_kernel<3, 0><<<gD, blk256, 0, stream>>>(ctxbf, wt_o, bo, xcur, xcur,
                                                nullptr, M, Dn, Dn);

  // conv module
  ln_kernel<1, 0><<<grid_rows, blk256, 0, stream>>>(xcur, cv_g, cv_b, y,
                                                    nullptr, pw1w, pw1b);
  conv_kernel<<<grid_rows, blk256, 0, stream>>>(y, dww, dwb, pw2w, pw2b, xcur);

  // macaron FFN-out
  ln_kernel<0, 1><<<grid_rows, blk256, 0, stream>>>(xcur, fo_g, fo_b, nullptr,
                                                    ybf, nullptr, nullptr);
  mgemm_kernel<0, 0><<<gF, blk256, 0, stream>>>(ybf, wt_fo1, fo_b1, nullptr,
                                                nullptr, hbf, M, Fn, Dn);
  mgemm_kernel<1, 0><<<gD, blk256, 0, stream>>>(hbf, wt_fo2, fo_b2, xcur, xcur,
                                                nullptr, M, Dn, Fn);

  // final LN -> d_out[0]
  ln_kernel<0, 0><<<grid_rows, blk256, 0, stream>>>(xcur, fl_g, fl_b, out,
                                                    nullptr, nullptr, nullptr);

  // passthrough outputs (AFTER all scratch use of the out region)
  hipMemcpyAsync(out + N_OUT, pos_k, N_POSK * sizeof(float),
                 hipMemcpyDeviceToDevice, stream);
  i2f_kernel<<<dim3((N_MASK / 4 + 255) / 256), blk256, 0, stream>>>(
      mask, out + N_OUT + N_POSK, N_MASK / 4);
}

// Round 5
// 590.362 us; speedup vs baseline: 8.2621x; 1.4382x over previous
//
#include <hip/hip_runtime.h>
#include <math.h>

static constexpr int Bsz = 4, Tn = 1024, Dn = 512, Hn = 8, Fn = 2048, Kw = 31, Dk = 64;
static constexpr size_t N_OUT  = (size_t)Bsz * Tn * Dn;   // 2,097,152
static constexpr size_t N_POSK = (size_t)Tn * Tn * Dk;    // 67,108,864
static constexpr size_t N_MASK = (size_t)Bsz * Tn * Tn;   // 4,194,304

typedef __attribute__((ext_vector_type(8))) short bhalf8;  // 8 bf16 (4 VGPR)
typedef __attribute__((ext_vector_type(4))) float f4;      // MFMA C/D

__device__ __forceinline__ ushort f2b(float f) {
  uint b = __float_as_uint(f);
  uint r = (b + 0x7FFFu + ((b >> 16) & 1u)) >> 16;
  return (ushort)r;
}

// ---------------------------------------------------------------------------
// LayerNorm; BF=1 -> bf16 output, BF=0 -> fp32 output. GLU on fp32 path.
// ---------------------------------------------------------------------------
template <int GLU, int BF>
__global__ __launch_bounds__(256) void ln_kernel(
    const float* __restrict__ x, const float* __restrict__ g,
    const float* __restrict__ b, float* __restrict__ yf,
    ushort* __restrict__ yb, const float* __restrict__ pw1w,
    const float* __restrict__ pw1b) {
  const int row = blockIdx.x;
  const float* xr = x + (size_t)row * Dn;
  const int tid = threadIdx.x, wid = tid >> 6, lane = tid & 63;

  __shared__ float red[4];
  __shared__ float bc[2];

  float v0 = xr[tid], v1 = xr[tid + 256];
  float s = v0 + v1;
#pragma unroll
  for (int off = 32; off; off >>= 1) s += __shfl_xor(s, off);
  if (lane == 0) red[wid] = s;
  __syncthreads();
  if (tid == 0) bc[0] = (red[0] + red[1] + red[2] + red[3]) * (1.0f / Dn);
  __syncthreads();
  const float m = bc[0];
  const float d0 = v0 - m, d1 = v1 - m;
  float s2 = d0 * d0 + d1 * d1;
#pragma unroll
  for (int off = 32; off; off >>= 1) s2 += __shfl_xor(s2, off);
  if (lane == 0) red[wid] = s2;
  __syncthreads();
  if (tid == 0)
    bc[1] = rsqrtf((red[0] + red[1] + red[2] + red[3]) * (1.0f / Dn) + 1e-5f);
  __syncthreads();
  const float r = bc[1];

  float o0 = d0 * r * g[tid] + b[tid];
  float o1 = d1 * r * g[tid + 256] + b[tid + 256];
  if (GLU) {
    const float w0 = pw1w[0], w1 = pw1w[1], c0 = pw1b[0], c1 = pw1b[1];
    o0 = (w0 * o0 + c0) * (1.0f / (1.0f + expf(-(w1 * o0 + c1))));
    o1 = (w0 * o1 + c0) * (1.0f / (1.0f + expf(-(w1 * o1 + c1))));
  }
  if (BF) {
    yb[(size_t)row * Dn + tid] = f2b(o0);
    yb[(size_t)row * Dn + tid + 256] = f2b(o1);
  } else {
    yf[(size_t)row * Dn + tid] = o0;
    yf[(size_t)row * Dn + tid + 256] = o1;
  }
}

// ---------------------------------------------------------------------------
// Weight convert+transpose: W (K x N fp32, row-major) -> Wt (N x K bf16)
// ---------------------------------------------------------------------------
__global__ __launch_bounds__(256) void wcvt_kernel(const float* __restrict__ W,
                                                   ushort* __restrict__ Wt,
                                                   int K, int N) {
  __shared__ float tile[32][33];
  const int n0 = blockIdx.x * 32, k0 = blockIdx.y * 32;
  const int tx = threadIdx.x & 31, ty = threadIdx.x >> 5;
#pragma unroll
  for (int i = 0; i < 4; ++i) {
    int k = ty + i * 8;
    tile[k][tx] = W[(size_t)(k0 + k) * N + n0 + tx];
  }
  __syncthreads();
#pragma unroll
  for (int i = 0; i < 4; ++i) {
    int r = ty + i * 8;
    Wt[(size_t)(n0 + r) * K + k0 + tx] = f2b(tile[tx][r]);
  }
}

// ---------------------------------------------------------------------------
// bf16 MFMA GEMM (NT): C(M,N) = epi(A(M,K)bf16 @ Bt(N,K)bf16^T + bias)
// MODE 0: relu -> bf16 Cb
// MODE 1: C = res + 0.5*v (fp32)
// MODE 3: C = res + v (fp32)
// MODE 4: Cb = bf16(v)  (no fp32 out)
// ---------------------------------------------------------------------------
template <int MODE>
__global__ __launch_bounds__(256) void mgemm_kernel(
    const ushort* __restrict__ A, const ushort* __restrict__ Bt,
    const float* __restrict__ bias, const float* __restrict__ res,
    float* __restrict__ C, ushort* __restrict__ Cb, int M, int N, int K) {
  __shared__ ushort As[128 * 64];
  __shared__ ushort Bs[128 * 64];
  const int bm = blockIdx.y * 128, bn = blockIdx.x * 128;
  const int tid = threadIdx.x;
  const int wid = tid >> 6, l = tid & 63;
  const int wm = wid >> 1, wn = wid & 1;
  const int l16 = l & 15, lhi = l >> 4;

  f4 acc[4][4] = {};

  for (int k0 = 0; k0 < K; k0 += 64) {
#pragma unroll
    for (int i = 0; i < 4; ++i) {
      int slot = tid + i * 256;
      int row = slot >> 3, c8 = slot & 7;
      *(uint4*)&As[row * 64 + c8 * 8] =
          *(const uint4*)(A + (size_t)(bm + row) * K + k0 + c8 * 8);
      *(uint4*)&Bs[row * 64 + c8 * 8] =
          *(const uint4*)(Bt + (size_t)(bn + row) * K + k0 + c8 * 8);
    }
    __syncthreads();
#pragma unroll
    for (int ks = 0; ks < 2; ++ks) {
      bhalf8 a[4], b[4];
#pragma unroll
      for (int mi = 0; mi < 4; ++mi)
        a[mi] = *(const bhalf8*)&As[(wm * 64 + mi * 16 + l16) * 64 + ks * 32 +
                                    lhi * 8];
#pragma unroll
      for (int ni = 0; ni < 4; ++ni)
        b[ni] = *(const bhalf8*)&Bs[(wn * 64 + ni * 16 + l16) * 64 + ks * 32 +
                                    lhi * 8];
#pragma unroll
      for (int mi = 0; mi < 4; ++mi)
#pragma unroll
        for (int ni = 0; ni < 4; ++ni)
          acc[mi][ni] = __builtin_amdgcn_mfma_f32_16x16x32_bf16(
              a[mi], b[ni], acc[mi][ni], 0, 0, 0);
    }
    __syncthreads();
  }

#pragma unroll
  for (int mi = 0; mi < 4; ++mi) {
#pragma unroll
    for (int ni = 0; ni < 4; ++ni) {
      const int col = bn + wn * 64 + ni * 16 + l16;
      const float bv = bias[col];
#pragma unroll
      for (int r = 0; r < 4; ++r) {
        const int row = bm + wm * 64 + mi * 16 + lhi * 4 + r;
        float v = acc[mi][ni][r] + bv;
        const size_t off = (size_t)row * N + col;
        if (MODE == 0) {
          Cb[off] = f2b(fmaxf(v, 0.0f));
        } else if (MODE == 4) {
          Cb[off] = f2b(v);
        } else {
          if (MODE == 1) v = res[off] + 0.5f * v;
          if (MODE == 3) v = res[off] + v;
          C[off] = v;
        }
      }
    }
  }
}

// ---------------------------------------------------------------------------
// bmm_kernel: Sc[bh][t][s] = q[b,t,h,:] . pos_k[t,s,:] via MFMA.
// ---------------------------------------------------------------------------
__global__ __launch_bounds__(256) void bmm_kernel(const ushort* __restrict__ qbf,
                                                  const float* __restrict__ pk,
                                                  float* __restrict__ Sc) {
  const int s0 = blockIdx.x * 256;
  const int t = blockIdx.y;
  const int tid = threadIdx.x, wid = tid >> 6, l = tid & 63;
  const int l16 = l & 15, lhi = l >> 4;

  __shared__ ushort Qs[32 * 64];
  __shared__ ushort Ps[256 * 64];

  {
    int row = tid >> 3, c8 = tid & 7;
    int bq = row >> 3, hq = row & 7;
    *(uint4*)&Qs[row * 64 + c8 * 8] =
        *(const uint4*)(qbf + ((size_t)(bq * Tn + t)) * Dn + hq * 64 + c8 * 8);
  }
#pragma unroll
  for (int i = 0; i < 16; ++i) {
    int slot = tid + i * 256;
    int sr = slot >> 4, c4 = slot & 15;
    const float4 p =
        *(const float4*)(pk + ((size_t)t * Tn + s0 + sr) * Dk + c4 * 4);
    ushort4 u;
    u.x = f2b(p.x);
    u.y = f2b(p.y);
    u.z = f2b(p.z);
    u.w = f2b(p.w);
    *(ushort4*)&Ps[sr * 64 + c4 * 4] = u;
  }
  __syncthreads();

  f4 acc[2][4] = {};
#pragma unroll
  for (int ks = 0; ks < 2; ++ks) {
    bhalf8 a[2], b[4];
#pragma unroll
    for (int mi = 0; mi < 2; ++mi)
      a[mi] = *(const bhalf8*)&Qs[(mi * 16 + l16) * 64 + ks * 32 + lhi * 8];
#pragma unroll
    for (int ni = 0; ni < 4; ++ni)
      b[ni] = *(const bhalf8*)&Ps[(wid * 64 + ni * 16 + l16) * 64 + ks * 32 +
                                  lhi * 8];
#pragma unroll
    for (int mi = 0; mi < 2; ++mi)
#pragma unroll
      for (int ni = 0; ni < 4; ++ni)
        acc[mi][ni] = __builtin_amdgcn_mfma_f32_16x16x32_bf16(
            a[mi], b[ni], acc[mi][ni], 0, 0, 0);
  }

#pragma unroll
  for (int mi = 0; mi < 2; ++mi)
#pragma unroll
    for (int ni = 0; ni < 4; ++ni)
#pragma unroll
      for (int r = 0; r < 4; ++r) {
        const int bh = mi * 16 + lhi * 4 + r;
        const int s = s0 + wid * 64 + ni * 16 + l16;
        Sc[((size_t)bh * Tn + t) * Tn + s] = acc[mi][ni][r];
      }
}

// ---------------------------------------------------------------------------
// qkm_kernel: Sc[bh][t][s] = (Sc + Q.K^T)*scale, masked -> -3e38  (bf16 MFMA)
// grid (s-tile, t-tile, bh); 128x128 tile, K=64.
// ---------------------------------------------------------------------------
__global__ __launch_bounds__(256) void qkm_kernel(
    const ushort* __restrict__ qbf, const ushort* __restrict__ kbf,
    const int* __restrict__ mask, float* __restrict__ Sc) {
  const int bh = blockIdx.z;
  const int b = bh >> 3, h = bh & 7;
  const int bm = blockIdx.y * 128;  // t
  const int bn = blockIdx.x * 128;  // s
  const int tid = threadIdx.x;
  const int wid = tid >> 6, l = tid & 63;
  const int wm = wid >> 1, wn = wid & 1;
  const int l16 = l & 15, lhi = l >> 4;

  __shared__ ushort Qs[128 * 64];
  __shared__ ushort Ks[128 * 64];

#pragma unroll
  for (int i = 0; i < 4; ++i) {
    int slot = tid + i * 256;
    int row = slot >> 3, c8 = slot & 7;
    *(uint4*)&Qs[row * 64 + c8 * 8] = *(const uint4*)(
        qbf + ((size_t)(b * Tn + bm + row)) * Dn + h * 64 + c8 * 8);
    *(uint4*)&Ks[row * 64 + c8 * 8] = *(const uint4*)(
        kbf + ((size_t)(b * Tn + bn + row)) * Dn + h * 64 + c8 * 8);
  }
  __syncthreads();

  f4 acc[4][4] = {};
#pragma unroll
  for (int ks = 0; ks < 2; ++ks) {
    bhalf8 a[4], bb[4];
#pragma unroll
    for (int mi = 0; mi < 4; ++mi)
      a[mi] = *(const bhalf8*)&Qs[(wm * 64 + mi * 16 + l16) * 64 + ks * 32 +
                                  lhi * 8];
#pragma unroll
    for (int ni = 0; ni < 4; ++ni)
      bb[ni] = *(const bhalf8*)&Ks[(wn * 64 + ni * 16 + l16) * 64 + ks * 32 +
                                   lhi * 8];
#pragma unroll
    for (int mi = 0; mi < 4; ++mi)
#pragma unroll
      for (int ni = 0; ni < 4; ++ni)
        acc[mi][ni] = __builtin_amdgcn_mfma_f32_16x16x32_bf16(
            a[mi], bb[ni], acc[mi][ni], 0, 0, 0);
  }

  const float scale = 0.125f;
#pragma unroll
  for (int mi = 0; mi < 4; ++mi) {
#pragma unroll
    for (int ni = 0; ni < 4; ++ni) {
      const int col = bn + wn * 64 + ni * 16 + l16;
#pragma unroll
      for (int r = 0; r < 4; ++r) {
        const int row = bm + wm * 64 + mi * 16 + lhi * 4 + r;
        const size_t off = ((size_t)bh * Tn + row) * Tn + col;
        float v = (Sc[off] + acc[mi][ni][r]) * scale;
        if (mask[((size_t)b * Tn + row) * Tn + col] == 0) v = -3.0e38f;
        Sc[off] = v;
      }
    }
  }
}

// ---------------------------------------------------------------------------
// softmax_kernel: row softmax over Tn=1024; reads Sc fp32, writes pbf bf16.
// ---------------------------------------------------------------------------
__global__ __launch_bounds__(256) void softmax_kernel(
    const float* __restrict__ Sc, ushort* __restrict__ pbf) {
  const float* r = Sc + (size_t)blockIdx.x * Tn;
  const int tid = threadIdx.x, wid = tid >> 6, lane = tid & 63;
  __shared__ float red[4];
  __shared__ float bcv[2];

  float4 v = ((const float4*)r)[tid];
  float mx = fmaxf(fmaxf(v.x, v.y), fmaxf(v.z, v.w));
#pragma unroll
  for (int off = 32; off; off >>= 1) mx = fmaxf(mx, __shfl_xor(mx, off));
  if (lane == 0) red[wid] = mx;
  __syncthreads();
  if (tid == 0) bcv[0] = fmaxf(fmaxf(red[0], red[1]), fmaxf(red[2], red[3]));
  __syncthreads();
  mx = bcv[0];

  v.x = __expf(v.x - mx);
  v.y = __expf(v.y - mx);
  v.z = __expf(v.z - mx);
  v.w = __expf(v.w - mx);
  float ss = v.x + v.y + v.z + v.w;
#pragma unroll
  for (int off = 32; off; off >>= 1) ss += __shfl_xor(ss, off);
  if (lane == 0) red[wid] = ss;
  __syncthreads();
  if (tid == 0)
    bcv[1] = 1.0f / fmaxf(red[0] + red[1] + red[2] + red[3], 1e-30f);
  __syncthreads();
  const float inv = bcv[1];
  ushort4 u;
  u.x = f2b(v.x * inv);
  u.y = f2b(v.y * inv);
  u.z = f2b(v.z * inv);
  u.w = f2b(v.w * inv);
  *(ushort4*)(pbf + (size_t)blockIdx.x * Tn + tid * 4) = u;
}

// ---------------------------------------------------------------------------
// pvm_kernel: ctxb[b,t,h*64+d] = sum_s P[bh][t][s] * v[b,s,h*64+d]  (MFMA)
// grid (t-tile 128, bh); V transposed in LDS (stride 66 -> ~2-way conflicts).
// ---------------------------------------------------------------------------
__global__ __launch_bounds__(256) void pvm_kernel(
    const ushort* __restrict__ pbf, const ushort* __restrict__ vbf,
    ushort* __restrict__ ctxb) {
  const int bh = blockIdx.y;
  const int b = bh >> 3, h = bh & 7;
  const int t0 = blockIdx.x * 128;
  const int tid = threadIdx.x;
  const int wid = tid >> 6, l = tid & 63;
  const int l16 = l & 15, lhi = l >> 4;

  __shared__ ushort Ps[128 * 64];  // 16 KB
  __shared__ ushort Vt[64 * 66];   // 8.25 KB, transposed V [d][s]

  f4 acc[2][4] = {};

  for (int s0 = 0; s0 < Tn; s0 += 64) {
    // stage P[128 t][64 s]
#pragma unroll
    for (int i = 0; i < 4; ++i) {
      int slot = tid + i * 256;
      int row = slot >> 3, c8 = slot & 7;
      *(uint4*)&Ps[row * 64 + c8 * 8] = *(const uint4*)(
          pbf + ((size_t)bh * Tn + t0 + row) * Tn + s0 + c8 * 8);
    }
    // stage Vt[d][s] transposed from vbf[s][d]
#pragma unroll
    for (int i = 0; i < 2; ++i) {
      int slot = tid + i * 256;
      int sr = slot >> 3, c8 = slot & 7;
      const uint4 raw = *(const uint4*)(
          vbf + ((size_t)(b * Tn + s0 + sr)) * Dn + h * 64 + c8 * 8);
      const ushort* e = (const ushort*)&raw;
#pragma unroll
      for (int j = 0; j < 8; ++j) Vt[(c8 * 8 + j) * 66 + sr] = e[j];
    }
    __syncthreads();
#pragma unroll
    for (int ks = 0; ks < 2; ++ks) {
      bhalf8 a[2], bb[4];
#pragma unroll
      for (int mi = 0; mi < 2; ++mi)
        a[mi] = *(const bhalf8*)&Ps[(wid * 32 + mi * 16 + l16) * 64 + ks * 32 +
                                    lhi * 8];
#pragma unroll
      for (int ni = 0; ni < 4; ++ni)
        bb[ni] = *(const bhalf8*)&Vt[(ni * 16 + l16) * 66 + ks * 32 + lhi * 8];
#pragma unroll
      for (int mi = 0; mi < 2; ++mi)
#pragma unroll
        for (int ni = 0; ni < 4; ++ni)
          acc[mi][ni] = __builtin_amdgcn_mfma_f32_16x16x32_bf16(
              a[mi], bb[ni], acc[mi][ni], 0, 0, 0);
    }
    __syncthreads();
  }

#pragma unroll
  for (int mi = 0; mi < 2; ++mi)
#pragma unroll
    for (int ni = 0; ni < 4; ++ni)
#pragma unroll
      for (int r = 0; r < 4; ++r) {
        const int t = t0 + wid * 32 + mi * 16 + lhi * 4 + r;
        const int d = ni * 16 + l16;
        ctxb[((size_t)(b * Tn + t)) * Dn + h * 64 + d] = f2b(acc[mi][ni][r]);
      }
}

// ---------------------------------------------------------------------------
// conv2: depthwise conv1d (K=31) + ReLU + pw2 + residual; register window.
// grid (T/16, D/256, B); thread owns channel d, 16 consecutive t outputs.
// ---------------------------------------------------------------------------
__global__ __launch_bounds__(256) void conv2_kernel(
    const float* __restrict__ y, const float* __restrict__ dww,
    const float* __restrict__ dwb, const float* __restrict__ pw2w,
    const float* __restrict__ pw2b, float* __restrict__ x) {
  const int b = blockIdx.z;
  const int d0 = blockIdx.y * 256;
  const int t0 = blockIdx.x * 16;
  const int tid = threadIdx.x;
  const int d = d0 + tid;

  __shared__ float wlds[256 * Kw];
#pragma unroll
  for (int i = 0; i < Kw; ++i)
    wlds[i * 256 + tid] = dww[(size_t)d0 * Kw + i * 256 + tid];
  __syncthreads();

  float w[Kw];
#pragma unroll
  for (int k = 0; k < Kw; ++k) w[k] = wlds[tid * Kw + k];  // stride 31: conflict-free

  float v[46];
#pragma unroll
  for (int i = 0; i < 46; ++i) {
    int t = t0 - 15 + i;
    v[i] = (t >= 0 && t < Tn) ? y[((size_t)b * Tn + t) * Dn + d] : 0.0f;
  }

  const float bias = dwb[d], w2 = pw2w[0], c2 = pw2b[0];
#pragma unroll
  for (int j = 0; j < 16; ++j) {
    float acc = bias;
#pragma unroll
    for (int k = 0; k < Kw; ++k) acc += w[k] * v[j + k];
    acc = fmaxf(acc, 0.0f);
    const size_t idx = ((size_t)b * Tn + t0 + j) * Dn + d;
    x[idx] = x[idx] + w2 * acc + c2;
  }
}

// ---------------------------------------------------------------------------
// int32 -> float32 conversion (mask passthrough)
// ---------------------------------------------------------------------------
__global__ __launch_bounds__(256) void i2f_kernel(const int* __restrict__ in,
                                                  float* __restrict__ out,
                                                  size_t n4) {
  size_t i = (size_t)blockIdx.x * 256 + threadIdx.x;
  if (i < n4) {
    const int4 v = ((const int4*)in)[i];
    float4 f;
    f.x = (float)v.x;
    f.y = (float)v.y;
    f.z = (float)v.z;
    f.w = (float)v.w;
    ((float4*)out)[i] = f;
  }
}

// ---------------------------------------------------------------------------
extern "C" void kernel_launch(void* const* d_in, const int* in_sizes, int n_in,
                              void* d_out, int out_size, void* d_ws,
                              size_t ws_size, hipStream_t stream) {
  const float* x = (const float*)d_in[0];
  const float* pos_k = (const float*)d_in[1];
  const int* mask = (const int*)d_in[2];
  const float* fi_g = (const float*)d_in[3];
  const float* fi_b = (const float*)d_in[4];
  const float* fi_w1 = (const float*)d_in[5];
  const float* fi_b1 = (const float*)d_in[6];
  const float* fi_w2 = (const float*)d_in[7];
  const float* fi_b2 = (const float*)d_in[8];
  const float* at_g = (const float*)d_in[9];
  const float* at_b = (const float*)d_in[10];
  const float* wq = (const float*)d_in[11];
  const float* bq = (const float*)d_in[12];
  const float* wk = (const float*)d_in[13];
  const float* bk = (const float*)d_in[14];
  const float* wv = (const float*)d_in[15];
  const float* bv = (const float*)d_in[16];
  const float* wo = (const float*)d_in[17];
  const float* bo = (const float*)d_in[18];
  const float* cv_g = (const float*)d_in[19];
  const float* cv_b = (const float*)d_in[20];
  const float* pw1w = (const float*)d_in[21];
  const float* pw1b = (const float*)d_in[22];
  const float* dww = (const float*)d_in[23];
  const float* dwb = (const float*)d_in[24];
  const float* pw2w = (const float*)d_in[25];
  const float* pw2b = (const float*)d_in[26];
  const float* fo_g = (const float*)d_in[27];
  const float* fo_b = (const float*)d_in[28];
  const float* fo_w1 = (const float*)d_in[29];
  const float* fo_b1 = (const float*)d_in[30];
  const float* fo_w2 = (const float*)d_in[31];
  const float* fo_b2 = (const float*)d_in[32];
  const float* fl_g = (const float*)d_in[33];
  const float* fl_b = (const float*)d_in[34];

  float* out = (float*)d_out;
  float* ws = (float*)d_ws;

  // fp32 workspace: xcur[2M] | y[2M]
  float* xcur = ws;
  float* y = ws + N_OUT;

  // scores scratch (B*H*T*T fp32 = 134 MB): first half of pos_k passthrough
  float* Sc = out + N_OUT;
  // bf16 scratch: second half of pos_k passthrough region (134 MB)
  ushort* p16 = (ushort*)(out + N_OUT + N_POSK / 2);
  ushort* wt_fi1 = p16;            p16 += (size_t)Fn * Dn;
  ushort* wt_fi2 = p16;            p16 += (size_t)Dn * Fn;
  ushort* wt_q = p16;              p16 += (size_t)Dn * Dn;
  ushort* wt_k = p16;              p16 += (size_t)Dn * Dn;
  ushort* wt_v = p16;              p16 += (size_t)Dn * Dn;
  ushort* wt_o = p16;              p16 += (size_t)Dn * Dn;
  ushort* wt_fo1 = p16;            p16 += (size_t)Fn * Dn;
  ushort* wt_fo2 = p16;            p16 += (size_t)Dn * Fn;
  ushort* ybf = p16;               p16 += N_OUT;
  ushort* hbf = p16;               p16 += (size_t)Bsz * Tn * Fn;
  ushort* ctxbf = p16;             p16 += N_OUT;
  ushort* qbf = p16;               p16 += N_OUT;
  ushort* kbf = p16;               p16 += N_OUT;
  ushort* vbf = p16;               p16 += N_OUT;
  ushort* pbf = p16;               p16 += (size_t)32 * Tn * Tn;  // 67 MB

  const int M = Bsz * Tn;  // 4096
  const dim3 blk256(256);
  const dim3 grid_rows(M);
  const dim3 gF(Fn / 128, M / 128);
  const dim3 gD(Dn / 128, M / 128);

  hipMemcpyAsync(xcur, x, N_OUT * sizeof(float), hipMemcpyDeviceToDevice,
                 stream);

  // weight conversions (fp32 KxN -> bf16 NxK)
  wcvt_kernel<<<dim3(Fn / 32, Dn / 32), blk256, 0, stream>>>(fi_w1, wt_fi1, Dn, Fn);
  wcvt_kernel<<<dim3(Dn / 32, Fn / 32), blk256, 0, stream>>>(fi_w2, wt_fi2, Fn, Dn);
  wcvt_kernel<<<dim3(Dn / 32, Dn / 32), blk256, 0, stream>>>(wq, wt_q, Dn, Dn);
  wcvt_kernel<<<dim3(Dn / 32, Dn / 32), blk256, 0, stream>>>(wk, wt_k, Dn, Dn);
  wcvt_kernel<<<dim3(Dn / 32, Dn / 32), blk256, 0, stream>>>(wv, wt_v, Dn, Dn);
  wcvt_kernel<<<dim3(Dn / 32, Dn / 32), blk256, 0, stream>>>(wo, wt_o, Dn, Dn);
  wcvt_kernel<<<dim3(Fn / 32, Dn / 32), blk256, 0, stream>>>(fo_w1, wt_fo1, Dn, Fn);
  wcvt_kernel<<<dim3(Dn / 32, Fn / 32), blk256, 0, stream>>>(fo_w2, wt_fo2, Fn, Dn);

  // macaron FFN-in
  ln_kernel<0, 1><<<grid_rows, blk256, 0, stream>>>(xcur, fi_g, fi_b, nullptr,
                                                    ybf, nullptr, nullptr);
  mgemm_kernel<0><<<gF, blk256, 0, stream>>>(ybf, wt_fi1, fi_b1, nullptr,
                                             nullptr, hbf, M, Fn, Dn);
  mgemm_kernel<1><<<gD, blk256, 0, stream>>>(hbf, wt_fi2, fi_b2, xcur, xcur,
                                             nullptr, M, Dn, Fn);

  // attention: projections (bf16-only outputs)
  ln_kernel<0, 1><<<grid_rows, blk256, 0, stream>>>(xcur, at_g, at_b, nullptr,
                                                    ybf, nullptr, nullptr);
  mgemm_kernel<4><<<gD, blk256, 0, stream>>>(ybf, wt_q, bq, nullptr, nullptr,
                                             qbf, M, Dn, Dn);
  mgemm_kernel<4><<<gD, blk256, 0, stream>>>(ybf, wt_k, bk, nullptr, nullptr,
                                             kbf, M, Dn, Dn);
  mgemm_kernel<4><<<gD, blk256, 0, stream>>>(ybf, wt_v, bv, nullptr, nullptr,
                                             vbf, M, Dn, Dn);

  bmm_kernel<<<dim3(4, Tn), blk256, 0, stream>>>(qbf, pos_k, Sc);
  qkm_kernel<<<dim3(8, 8, 32), blk256, 0, stream>>>(qbf, kbf, mask, Sc);
  softmax_kernel<<<dim3(32 * Tn), blk256, 0, stream>>>(Sc, pbf);
  pvm_kernel<<<dim3(8, 32), blk256, 0, stream>>>(pbf, vbf, ctxbf);

  mgemm_kernel<3><<<gD, blk256, 0, stream>>>(ctxbf, wt_o, bo, xcur, xcur,
                                             nullptr, M, Dn, Dn);

  // conv module
  ln_kernel<1, 0><<<grid_rows, blk256, 0, stream>>>(xcur, cv_g, cv_b, y,
                                                    nullptr, pw1w, pw1b);
  conv2_kernel<<<dim3(Tn / 16, 2, Bsz), blk256, 0, stream>>>(y, dww, dwb, pw2w,
                                                             pw2b, xcur);

  // macaron FFN-out
  ln_kernel<0, 1><<<grid_rows, blk256, 0, stream>>>(xcur, fo_g, fo_b, nullptr,
                                                    ybf, nullptr, nullptr);
  mgemm_kernel<0><<<gF, blk256, 0, stream>>>(ybf, wt_fo1, fo_b1, nullptr,
                                             nullptr, hbf, M, Fn, Dn);
  mgemm_kernel<1><<<gD, blk256, 0, stream>>>(hbf, wt_fo2, fo_b2, xcur, xcur,
                                             nullptr, M, Dn, Fn);

  // final LN -> d_out[0]
  ln_kernel<0, 0><<<grid_rows, blk256, 0, stream>>>(xcur, fl_g, fl_b, out,
                                                    nullptr, nullptr, nullptr);

  // passthrough outputs (AFTER all scratch use of the out region)
  hipMemcpyAsync(out + N_OUT, pos_k, N_POSK * sizeof(float),
                 hipMemcpyDeviceToDevice, stream);
  i2f_kernel<<<dim3((N_MASK / 4 + 255) / 256), blk256, 0, stream>>>(
      mask, out + N_OUT + N_POSK, N_MASK / 4);
}

// Round 6
// 506.845 us; speedup vs baseline: 9.6236x; 1.1648x over previous
//
#include <hip/hip_runtime.h>
#include <math.h>

static constexpr int Bsz = 4, Tn = 1024, Dn = 512, Hn = 8, Fn = 2048, Kw = 31, Dk = 64;
static constexpr size_t N_OUT  = (size_t)Bsz * Tn * Dn;   // 2,097,152
static constexpr size_t N_POSK = (size_t)Tn * Tn * Dk;    // 67,108,864
static constexpr size_t N_MASK = (size_t)Bsz * Tn * Tn;   // 4,194,304

typedef __attribute__((ext_vector_type(8))) short bhalf8;  // 8 bf16 (4 VGPR)
typedef __attribute__((ext_vector_type(4))) float f4;      // MFMA C/D

__device__ __forceinline__ ushort f2b(float f) {
  uint b = __float_as_uint(f);
  uint r = (b + 0x7FFFu + ((b >> 16) & 1u)) >> 16;
  return (ushort)r;
}
__device__ __forceinline__ float b2f(ushort u) {
  return __uint_as_float((uint)u << 16);
}

// async global->LDS, 16 B per lane (m97/m193-verified path)
typedef const __attribute__((address_space(1))) unsigned int* gp1_t;
typedef __attribute__((address_space(3))) unsigned int* lp3_t;
__device__ __forceinline__ void gload16(const void* g, void* l) {
  __builtin_amdgcn_global_load_lds((gp1_t)g, (lp3_t)l, 16, 0, 0);
}

// ---------------------------------------------------------------------------
// LayerNorm; BF=1 -> bf16 output, BF=0 -> fp32 output. GLU on fp32 path.
// ---------------------------------------------------------------------------
template <int GLU, int BF>
__global__ __launch_bounds__(256) void ln_kernel(
    const float* __restrict__ x, const float* __restrict__ g,
    const float* __restrict__ b, float* __restrict__ yf,
    ushort* __restrict__ yb, const float* __restrict__ pw1w,
    const float* __restrict__ pw1b) {
  const int row = blockIdx.x;
  const float* xr = x + (size_t)row * Dn;
  const int tid = threadIdx.x, wid = tid >> 6, lane = tid & 63;

  __shared__ float red[4];
  __shared__ float bc[2];

  float v0 = xr[tid], v1 = xr[tid + 256];
  float s = v0 + v1;
#pragma unroll
  for (int off = 32; off; off >>= 1) s += __shfl_xor(s, off);
  if (lane == 0) red[wid] = s;
  __syncthreads();
  if (tid == 0) bc[0] = (red[0] + red[1] + red[2] + red[3]) * (1.0f / Dn);
  __syncthreads();
  const float m = bc[0];
  const float d0 = v0 - m, d1 = v1 - m;
  float s2 = d0 * d0 + d1 * d1;
#pragma unroll
  for (int off = 32; off; off >>= 1) s2 += __shfl_xor(s2, off);
  if (lane == 0) red[wid] = s2;
  __syncthreads();
  if (tid == 0)
    bc[1] = rsqrtf((red[0] + red[1] + red[2] + red[3]) * (1.0f / Dn) + 1e-5f);
  __syncthreads();
  const float r = bc[1];

  float o0 = d0 * r * g[tid] + b[tid];
  float o1 = d1 * r * g[tid + 256] + b[tid + 256];
  if (GLU) {
    const float w0 = pw1w[0], w1 = pw1w[1], c0 = pw1b[0], c1 = pw1b[1];
    o0 = (w0 * o0 + c0) * (1.0f / (1.0f + expf(-(w1 * o0 + c1))));
    o1 = (w0 * o1 + c0) * (1.0f / (1.0f + expf(-(w1 * o1 + c1))));
  }
  if (BF) {
    yb[(size_t)row * Dn + tid] = f2b(o0);
    yb[(size_t)row * Dn + tid + 256] = f2b(o1);
  } else {
    yf[(size_t)row * Dn + tid] = o0;
    yf[(size_t)row * Dn + tid + 256] = o1;
  }
}

// ---------------------------------------------------------------------------
// Weight convert+transpose: W (K x N fp32, row-major) -> Wt (N x K bf16)
// ---------------------------------------------------------------------------
__global__ __launch_bounds__(256) void wcvt_kernel(const float* __restrict__ W,
                                                   ushort* __restrict__ Wt,
                                                   int K, int N) {
  __shared__ float tile[32][33];
  const int n0 = blockIdx.x * 32, k0 = blockIdx.y * 32;
  const int tx = threadIdx.x & 31, ty = threadIdx.x >> 5;
#pragma unroll
  for (int i = 0; i < 4; ++i) {
    int k = ty + i * 8;
    tile[k][tx] = W[(size_t)(k0 + k) * N + n0 + tx];
  }
  __syncthreads();
#pragma unroll
  for (int i = 0; i < 4; ++i) {
    int r = ty + i * 8;
    Wt[(size_t)(n0 + r) * K + k0 + tx] = f2b(tile[tx][r]);
  }
}

// ---------------------------------------------------------------------------
// bf16 MFMA GEMM (NT): C(M,N) = epi(A(M,K)bf16 @ Bt(N,K)bf16^T + bias)
// global_load_lds staging (linear LDS layout, 16 B/lane).
// MODE 0: relu -> bf16 Cb     MODE 1: C = res + 0.5*v (fp32)
// MODE 3: C = res + v (fp32)  MODE 4: Cb = bf16(v)
// ---------------------------------------------------------------------------
template <int MODE>
__global__ __launch_bounds__(256) void mgemm_kernel(
    const ushort* __restrict__ A, const ushort* __restrict__ Bt,
    const float* __restrict__ bias, const float* __restrict__ res,
    float* __restrict__ C, ushort* __restrict__ Cb, int M, int N, int K) {
  __shared__ ushort As[128 * 64];
  __shared__ ushort Bs[128 * 64];
  const int bm = blockIdx.y * 128, bn = blockIdx.x * 128;
  const int tid = threadIdx.x;
  const int wid = tid >> 6, l = tid & 63;
  const int wm = wid >> 1, wn = wid & 1;
  const int l16 = l & 15, lhi = l >> 4;

  f4 acc[4][4] = {};

  for (int k0 = 0; k0 < K; k0 += 64) {
#pragma unroll
    for (int i = 0; i < 4; ++i) {
      int slot = tid + i * 256;
      int row = slot >> 3, c8 = slot & 7;
      gload16(A + (size_t)(bm + row) * K + k0 + c8 * 8, &As[slot * 8]);
      gload16(Bt + (size_t)(bn + row) * K + k0 + c8 * 8, &Bs[slot * 8]);
    }
    __syncthreads();
#pragma unroll
    for (int ks = 0; ks < 2; ++ks) {
      bhalf8 a[4], b[4];
#pragma unroll
      for (int mi = 0; mi < 4; ++mi)
        a[mi] = *(const bhalf8*)&As[(wm * 64 + mi * 16 + l16) * 64 + ks * 32 +
                                    lhi * 8];
#pragma unroll
      for (int ni = 0; ni < 4; ++ni)
        b[ni] = *(const bhalf8*)&Bs[(wn * 64 + ni * 16 + l16) * 64 + ks * 32 +
                                    lhi * 8];
#pragma unroll
      for (int mi = 0; mi < 4; ++mi)
#pragma unroll
        for (int ni = 0; ni < 4; ++ni)
          acc[mi][ni] = __builtin_amdgcn_mfma_f32_16x16x32_bf16(
              a[mi], b[ni], acc[mi][ni], 0, 0, 0);
    }
    __syncthreads();
  }

#pragma unroll
  for (int mi = 0; mi < 4; ++mi) {
#pragma unroll
    for (int ni = 0; ni < 4; ++ni) {
      const int col = bn + wn * 64 + ni * 16 + l16;
      const float bv = bias[col];
#pragma unroll
      for (int r = 0; r < 4; ++r) {
        const int row = bm + wm * 64 + mi * 16 + lhi * 4 + r;
        float v = acc[mi][ni][r] + bv;
        const size_t off = (size_t)row * N + col;
        if (MODE == 0) {
          Cb[off] = f2b(fmaxf(v, 0.0f));
        } else if (MODE == 4) {
          Cb[off] = f2b(v);
        } else {
          if (MODE == 1) v = res[off] + 0.5f * v;
          if (MODE == 3) v = res[off] + v;
          C[off] = v;
        }
      }
    }
  }
}

// ---------------------------------------------------------------------------
// bmm: Sc16[bh][t][s] = bf16( q . pos_k[t,s,:] ); PASS=1 also writes the
// pos_k passthrough copy (reads pos_k exactly once -> dedups the d2d copy).
// ---------------------------------------------------------------------------
template <int PASS>
__global__ __launch_bounds__(256) void bmm_kernel(const ushort* __restrict__ qbf,
                                                  const float* __restrict__ pk,
                                                  ushort* __restrict__ Sc16,
                                                  float* __restrict__ pkout) {
  const int s0 = blockIdx.x * 256;
  const int t = blockIdx.y;
  const int tid = threadIdx.x, wid = tid >> 6, l = tid & 63;
  const int l16 = l & 15, lhi = l >> 4;

  __shared__ ushort Qs[32 * 64];
  __shared__ ushort Ps[256 * 64];

  {
    int row = tid >> 3, c8 = tid & 7;
    int bq = row >> 3, hq = row & 7;
    *(uint4*)&Qs[row * 64 + c8 * 8] =
        *(const uint4*)(qbf + ((size_t)(bq * Tn + t)) * Dn + hq * 64 + c8 * 8);
  }
#pragma unroll
  for (int i = 0; i < 16; ++i) {
    int slot = tid + i * 256;
    int sr = slot >> 4, c4 = slot & 15;
    const size_t goff = ((size_t)t * Tn + s0 + sr) * Dk + c4 * 4;
    const float4 p = *(const float4*)(pk + goff);
    if (PASS) *(float4*)(pkout + goff) = p;
    ushort4 u;
    u.x = f2b(p.x);
    u.y = f2b(p.y);
    u.z = f2b(p.z);
    u.w = f2b(p.w);
    *(ushort4*)&Ps[sr * 64 + c4 * 4] = u;
  }
  __syncthreads();

  f4 acc[2][4] = {};
#pragma unroll
  for (int ks = 0; ks < 2; ++ks) {
    bhalf8 a[2], b[4];
#pragma unroll
    for (int mi = 0; mi < 2; ++mi)
      a[mi] = *(const bhalf8*)&Qs[(mi * 16 + l16) * 64 + ks * 32 + lhi * 8];
#pragma unroll
    for (int ni = 0; ni < 4; ++ni)
      b[ni] = *(const bhalf8*)&Ps[(wid * 64 + ni * 16 + l16) * 64 + ks * 32 +
                                  lhi * 8];
#pragma unroll
    for (int mi = 0; mi < 2; ++mi)
#pragma unroll
      for (int ni = 0; ni < 4; ++ni)
        acc[mi][ni] = __builtin_amdgcn_mfma_f32_16x16x32_bf16(
            a[mi], b[ni], acc[mi][ni], 0, 0, 0);
  }

#pragma unroll
  for (int mi = 0; mi < 2; ++mi)
#pragma unroll
    for (int ni = 0; ni < 4; ++ni)
#pragma unroll
      for (int r = 0; r < 4; ++r) {
        const int bh = mi * 16 + lhi * 4 + r;
        const int s = s0 + wid * 64 + ni * 16 + l16;
        Sc16[((size_t)bh * Tn + t) * Tn + s] = f2b(acc[mi][ni][r]);
      }
}

// ---------------------------------------------------------------------------
// qkm: Sc16[bh][t][s] = bf16( (Sc16 + Q.K^T)*scale ), masked -> -3e38
// ---------------------------------------------------------------------------
__global__ __launch_bounds__(256) void qkm_kernel(
    const ushort* __restrict__ qbf, const ushort* __restrict__ kbf,
    const int* __restrict__ mask, ushort* __restrict__ Sc16) {
  const int bh = blockIdx.z;
  const int b = bh >> 3, h = bh & 7;
  const int bm = blockIdx.y * 128;  // t
  const int bn = blockIdx.x * 128;  // s
  const int tid = threadIdx.x;
  const int wid = tid >> 6, l = tid & 63;
  const int wm = wid >> 1, wn = wid & 1;
  const int l16 = l & 15, lhi = l >> 4;

  __shared__ ushort Qs[128 * 64];
  __shared__ ushort Ks[128 * 64];

#pragma unroll
  for (int i = 0; i < 4; ++i) {
    int slot = tid + i * 256;
    int row = slot >> 3, c8 = slot & 7;
    gload16(qbf + ((size_t)(b * Tn + bm + row)) * Dn + h * 64 + c8 * 8,
            &Qs[slot * 8]);
    gload16(kbf + ((size_t)(b * Tn + bn + row)) * Dn + h * 64 + c8 * 8,
            &Ks[slot * 8]);
  }
  __syncthreads();

  f4 acc[4][4] = {};
#pragma unroll
  for (int ks = 0; ks < 2; ++ks) {
    bhalf8 a[4], bb[4];
#pragma unroll
    for (int mi = 0; mi < 4; ++mi)
      a[mi] = *(const bhalf8*)&Qs[(wm * 64 + mi * 16 + l16) * 64 + ks * 32 +
                                  lhi * 8];
#pragma unroll
    for (int ni = 0; ni < 4; ++ni)
      bb[ni] = *(const bhalf8*)&Ks[(wn * 64 + ni * 16 + l16) * 64 + ks * 32 +
                                   lhi * 8];
#pragma unroll
    for (int mi = 0; mi < 4; ++mi)
#pragma unroll
      for (int ni = 0; ni < 4; ++ni)
        acc[mi][ni] = __builtin_amdgcn_mfma_f32_16x16x32_bf16(
            a[mi], bb[ni], acc[mi][ni], 0, 0, 0);
  }

  const float scale = 0.125f;
#pragma unroll
  for (int mi = 0; mi < 4; ++mi) {
#pragma unroll
    for (int ni = 0; ni < 4; ++ni) {
      const int col = bn + wn * 64 + ni * 16 + l16;
#pragma unroll
      for (int r = 0; r < 4; ++r) {
        const int row = bm + wm * 64 + mi * 16 + lhi * 4 + r;
        const size_t off = ((size_t)bh * Tn + row) * Tn + col;
        float v = (b2f(Sc16[off]) + acc[mi][ni][r]) * scale;
        if (mask[((size_t)b * Tn + row) * Tn + col] == 0) v = -3.0e38f;
        Sc16[off] = f2b(v);
      }
    }
  }
}

// ---------------------------------------------------------------------------
// softmax: row softmax over Tn=1024; reads Sc16 bf16, writes pbf bf16.
// ---------------------------------------------------------------------------
__global__ __launch_bounds__(256) void softmax_kernel(
    const ushort* __restrict__ Sc16, ushort* __restrict__ pbf) {
  const ushort* r = Sc16 + (size_t)blockIdx.x * Tn;
  const int tid = threadIdx.x, wid = tid >> 6, lane = tid & 63;
  __shared__ float red[4];
  __shared__ float bcv[2];

  const ushort4 u = *(const ushort4*)(r + tid * 4);
  float v0 = b2f(u.x), v1 = b2f(u.y), v2 = b2f(u.z), v3 = b2f(u.w);
  float mx = fmaxf(fmaxf(v0, v1), fmaxf(v2, v3));
#pragma unroll
  for (int off = 32; off; off >>= 1) mx = fmaxf(mx, __shfl_xor(mx, off));
  if (lane == 0) red[wid] = mx;
  __syncthreads();
  if (tid == 0) bcv[0] = fmaxf(fmaxf(red[0], red[1]), fmaxf(red[2], red[3]));
  __syncthreads();
  mx = bcv[0];

  v0 = __expf(v0 - mx);
  v1 = __expf(v1 - mx);
  v2 = __expf(v2 - mx);
  v3 = __expf(v3 - mx);
  float ss = v0 + v1 + v2 + v3;
#pragma unroll
  for (int off = 32; off; off >>= 1) ss += __shfl_xor(ss, off);
  if (lane == 0) red[wid] = ss;
  __syncthreads();
  if (tid == 0)
    bcv[1] = 1.0f / fmaxf(red[0] + red[1] + red[2] + red[3], 1e-30f);
  __syncthreads();
  const float inv = bcv[1];
  ushort4 o;
  o.x = f2b(v0 * inv);
  o.y = f2b(v1 * inv);
  o.z = f2b(v2 * inv);
  o.w = f2b(v3 * inv);
  *(ushort4*)(pbf + (size_t)blockIdx.x * Tn + tid * 4) = o;
}

// ---------------------------------------------------------------------------
// pvm: ctxb[b,t,h*64+d] = sum_s P[bh][t][s] * v[b,s,h*64+d]  (MFMA)
// ---------------------------------------------------------------------------
__global__ __launch_bounds__(256) void pvm_kernel(
    const ushort* __restrict__ pbf, const ushort* __restrict__ vbf,
    ushort* __restrict__ ctxb) {
  const int bh = blockIdx.y;
  const int b = bh >> 3, h = bh & 7;
  const int t0 = blockIdx.x * 128;
  const int tid = threadIdx.x;
  const int wid = tid >> 6, l = tid & 63;
  const int l16 = l & 15, lhi = l >> 4;

  __shared__ ushort Ps[128 * 64];  // 16 KB
  __shared__ ushort Vt[64 * 66];   // transposed V [d][s]

  f4 acc[2][4] = {};

  for (int s0 = 0; s0 < Tn; s0 += 64) {
#pragma unroll
    for (int i = 0; i < 4; ++i) {
      int slot = tid + i * 256;
      int row = slot >> 3, c8 = slot & 7;
      gload16(pbf + ((size_t)bh * Tn + t0 + row) * Tn + s0 + c8 * 8,
              &Ps[slot * 8]);
    }
#pragma unroll
    for (int i = 0; i < 2; ++i) {
      int slot = tid + i * 256;
      int sr = slot >> 3, c8 = slot & 7;
      const uint4 raw = *(const uint4*)(
          vbf + ((size_t)(b * Tn + s0 + sr)) * Dn + h * 64 + c8 * 8);
      const ushort* e = (const ushort*)&raw;
#pragma unroll
      for (int j = 0; j < 8; ++j) Vt[(c8 * 8 + j) * 66 + sr] = e[j];
    }
    __syncthreads();
#pragma unroll
    for (int ks = 0; ks < 2; ++ks) {
      bhalf8 a[2], bb[4];
#pragma unroll
      for (int mi = 0; mi < 2; ++mi)
        a[mi] = *(const bhalf8*)&Ps[(wid * 32 + mi * 16 + l16) * 64 + ks * 32 +
                                    lhi * 8];
#pragma unroll
      for (int ni = 0; ni < 4; ++ni)
        bb[ni] = *(const bhalf8*)&Vt[(ni * 16 + l16) * 66 + ks * 32 + lhi * 8];
#pragma unroll
      for (int mi = 0; mi < 2; ++mi)
#pragma unroll
        for (int ni = 0; ni < 4; ++ni)
          acc[mi][ni] = __builtin_amdgcn_mfma_f32_16x16x32_bf16(
              a[mi], bb[ni], acc[mi][ni], 0, 0, 0);
    }
    __syncthreads();
  }

#pragma unroll
  for (int mi = 0; mi < 2; ++mi)
#pragma unroll
    for (int ni = 0; ni < 4; ++ni)
#pragma unroll
      for (int r = 0; r < 4; ++r) {
        const int t = t0 + wid * 32 + mi * 16 + lhi * 4 + r;
        const int d = ni * 16 + l16;
        ctxb[((size_t)(b * Tn + t)) * Dn + h * 64 + d] = f2b(acc[mi][ni][r]);
      }
}

// ---------------------------------------------------------------------------
// conv2: depthwise conv1d (K=31) + ReLU + pw2 + residual; register window.
// ---------------------------------------------------------------------------
__global__ __launch_bounds__(256) void conv2_kernel(
    const float* __restrict__ y, const float* __restrict__ dww,
    const float* __restrict__ dwb, const float* __restrict__ pw2w,
    const float* __restrict__ pw2b, float* __restrict__ x) {
  const int b = blockIdx.z;
  const int d0 = blockIdx.y * 256;
  const int t0 = blockIdx.x * 16;
  const int tid = threadIdx.x;
  const int d = d0 + tid;

  __shared__ float wlds[256 * Kw];
#pragma unroll
  for (int i = 0; i < Kw; ++i)
    wlds[i * 256 + tid] = dww[(size_t)d0 * Kw + i * 256 + tid];
  __syncthreads();

  float w[Kw];
#pragma unroll
  for (int k = 0; k < Kw; ++k) w[k] = wlds[tid * Kw + k];

  float v[46];
#pragma unroll
  for (int i = 0; i < 46; ++i) {
    int t = t0 - 15 + i;
    v[i] = (t >= 0 && t < Tn) ? y[((size_t)b * Tn + t) * Dn + d] : 0.0f;
  }

  const float bias = dwb[d], w2 = pw2w[0], c2 = pw2b[0];
#pragma unroll
  for (int j = 0; j < 16; ++j) {
    float acc = bias;
#pragma unroll
    for (int k = 0; k < Kw; ++k) acc += w[k] * v[j + k];
    acc = fmaxf(acc, 0.0f);
    const size_t idx = ((size_t)b * Tn + t0 + j) * Dn + d;
    x[idx] = x[idx] + w2 * acc + c2;
  }
}

// ---------------------------------------------------------------------------
// int32 -> float32 conversion (mask passthrough)
// ---------------------------------------------------------------------------
__global__ __launch_bounds__(256) void i2f_kernel(const int* __restrict__ in,
                                                  float* __restrict__ out,
                                                  size_t n4) {
  size_t i = (size_t)blockIdx.x * 256 + threadIdx.x;
  if (i < n4) {
    const int4 v = ((const int4*)in)[i];
    float4 f;
    f.x = (float)v.x;
    f.y = (float)v.y;
    f.z = (float)v.z;
    f.w = (float)v.w;
    ((float4*)out)[i] = f;
  }
}

// ---------------------------------------------------------------------------
extern "C" void kernel_launch(void* const* d_in, const int* in_sizes, int n_in,
                              void* d_out, int out_size, void* d_ws,
                              size_t ws_size, hipStream_t stream) {
  const float* x = (const float*)d_in[0];
  const float* pos_k = (const float*)d_in[1];
  const int* mask = (const int*)d_in[2];
  const float* fi_g = (const float*)d_in[3];
  const float* fi_b = (const float*)d_in[4];
  const float* fi_w1 = (const float*)d_in[5];
  const float* fi_b1 = (const float*)d_in[6];
  const float* fi_w2 = (const float*)d_in[7];
  const float* fi_b2 = (const float*)d_in[8];
  const float* at_g = (const float*)d_in[9];
  const float* at_b = (const float*)d_in[10];
  const float* wq = (const float*)d_in[11];
  const float* bq = (const float*)d_in[12];
  const float* wk = (const float*)d_in[13];
  const float* bk = (const float*)d_in[14];
  const float* wv = (const float*)d_in[15];
  const float* bv = (const float*)d_in[16];
  const float* wo = (const float*)d_in[17];
  const float* bo = (const float*)d_in[18];
  const float* cv_g = (const float*)d_in[19];
  const float* cv_b = (const float*)d_in[20];
  const float* pw1w = (const float*)d_in[21];
  const float* pw1b = (const float*)d_in[22];
  const float* dww = (const float*)d_in[23];
  const float* dwb = (const float*)d_in[24];
  const float* pw2w = (const float*)d_in[25];
  const float* pw2b = (const float*)d_in[26];
  const float* fo_g = (const float*)d_in[27];
  const float* fo_b = (const float*)d_in[28];
  const float* fo_w1 = (const float*)d_in[29];
  const float* fo_b1 = (const float*)d_in[30];
  const float* fo_w2 = (const float*)d_in[31];
  const float* fo_b2 = (const float*)d_in[32];
  const float* fl_g = (const float*)d_in[33];
  const float* fl_b = (const float*)d_in[34];

  float* out = (float*)d_out;

  // xcur/y always in ws (needs only 16.8 MB; >=48 MB proven in R3)
  float* xcur = (float*)d_ws;
  float* y = xcur + N_OUT;

  // big scratch: prefer ws (enables fused pos_k passthrough); else out region
  const size_t NEED = (size_t)206 << 20;
  const bool fused = ws_size >= NEED;
  char* sp = fused ? (char*)(y + N_OUT) : (char*)(out + N_OUT);
  auto alloc16 = [&](size_t elems) {
    ushort* p = (ushort*)sp;
    sp += ((elems * 2 + 255) & ~(size_t)255);
    return p;
  };
  ushort* Sc16 = alloc16((size_t)32 * Tn * Tn);  // 67 MB
  ushort* pbf = alloc16((size_t)32 * Tn * Tn);   // 67 MB
  ushort* wt_fi1 = alloc16((size_t)Fn * Dn);
  ushort* wt_fi2 = alloc16((size_t)Dn * Fn);
  ushort* wt_q = alloc16((size_t)Dn * Dn);
  ushort* wt_k = alloc16((size_t)Dn * Dn);
  ushort* wt_v = alloc16((size_t)Dn * Dn);
  ushort* wt_o = alloc16((size_t)Dn * Dn);
  ushort* wt_fo1 = alloc16((size_t)Fn * Dn);
  ushort* wt_fo2 = alloc16((size_t)Dn * Fn);
  ushort* ybf = alloc16(N_OUT);
  ushort* hbf = alloc16((size_t)Bsz * Tn * Fn);
  ushort* ctxbf = alloc16(N_OUT);
  ushort* qbf = alloc16(N_OUT);
  ushort* kbf = alloc16(N_OUT);
  ushort* vbf = alloc16(N_OUT);

  const int M = Bsz * Tn;  // 4096
  const dim3 blk256(256);
  const dim3 grid_rows(M);
  const dim3 gF(Fn / 128, M / 128);
  const dim3 gD(Dn / 128, M / 128);

  hipMemcpyAsync(xcur, x, N_OUT * sizeof(float), hipMemcpyDeviceToDevice,
                 stream);

  // weight conversions (fp32 KxN -> bf16 NxK)
  wcvt_kernel<<<dim3(Fn / 32, Dn / 32), blk256, 0, stream>>>(fi_w1, wt_fi1, Dn, Fn);
  wcvt_kernel<<<dim3(Dn / 32, Fn / 32), blk256, 0, stream>>>(fi_w2, wt_fi2, Fn, Dn);
  wcvt_kernel<<<dim3(Dn / 32, Dn / 32), blk256, 0, stream>>>(wq, wt_q, Dn, Dn);
  wcvt_kernel<<<dim3(Dn / 32, Dn / 32), blk256, 0, stream>>>(wk, wt_k, Dn, Dn);
  wcvt_kernel<<<dim3(Dn / 32, Dn / 32), blk256, 0, stream>>>(wv, wt_v, Dn, Dn);
  wcvt_kernel<<<dim3(Dn / 32, Dn / 32), blk256, 0, stream>>>(wo, wt_o, Dn, Dn);
  wcvt_kernel<<<dim3(Fn / 32, Dn / 32), blk256, 0, stream>>>(fo_w1, wt_fo1, Dn, Fn);
  wcvt_kernel<<<dim3(Dn / 32, Fn / 32), blk256, 0, stream>>>(fo_w2, wt_fo2, Fn, Dn);

  // macaron FFN-in
  ln_kernel<0, 1><<<grid_rows, blk256, 0, stream>>>(xcur, fi_g, fi_b, nullptr,
                                                    ybf, nullptr, nullptr);
  mgemm_kernel<0><<<gF, blk256, 0, stream>>>(ybf, wt_fi1, fi_b1, nullptr,
                                             nullptr, hbf, M, Fn, Dn);
  mgemm_kernel<1><<<gD, blk256, 0, stream>>>(hbf, wt_fi2, fi_b2, xcur, xcur,
                                             nullptr, M, Dn, Fn);

  // attention projections (bf16 outputs)
  ln_kernel<0, 1><<<grid_rows, blk256, 0, stream>>>(xcur, at_g, at_b, nullptr,
                                                    ybf, nullptr, nullptr);
  mgemm_kernel<4><<<gD, blk256, 0, stream>>>(ybf, wt_q, bq, nullptr, nullptr,
                                             qbf, M, Dn, Dn);
  mgemm_kernel<4><<<gD, blk256, 0, stream>>>(ybf, wt_k, bk, nullptr, nullptr,
                                             kbf, M, Dn, Dn);
  mgemm_kernel<4><<<gD, blk256, 0, stream>>>(ybf, wt_v, bv, nullptr, nullptr,
                                             vbf, M, Dn, Dn);

  if (fused)
    bmm_kernel<1><<<dim3(4, Tn), blk256, 0, stream>>>(qbf, pos_k, Sc16,
                                                      out + N_OUT);
  else
    bmm_kernel<0><<<dim3(4, Tn), blk256, 0, stream>>>(qbf, pos_k, Sc16,
                                                      nullptr);
  qkm_kernel<<<dim3(8, 8, 32), blk256, 0, stream>>>(qbf, kbf, mask, Sc16);
  softmax_kernel<<<dim3(32 * Tn), blk256, 0, stream>>>(Sc16, pbf);
  pvm_kernel<<<dim3(8, 32), blk256, 0, stream>>>(pbf, vbf, ctxbf);

  mgemm_kernel<3><<<gD, blk256, 0, stream>>>(ctxbf, wt_o, bo, xcur, xcur,
                                             nullptr, M, Dn, Dn);

  // conv module
  ln_kernel<1, 0><<<grid_rows, blk256, 0, stream>>>(xcur, cv_g, cv_b, y,
                                                    nullptr, pw1w, pw1b);
  conv2_kernel<<<dim3(Tn / 16, 2, Bsz), blk256, 0, stream>>>(y, dww, dwb, pw2w,
                                                             pw2b, xcur);

  // macaron FFN-out
  ln_kernel<0, 1><<<grid_rows, blk256, 0, stream>>>(xcur, fo_g, fo_b, nullptr,
                                                    ybf, nullptr, nullptr);
  mgemm_kernel<0><<<gF, blk256, 0, stream>>>(ybf, wt_fo1, fo_b1, nullptr,
                                             nullptr, hbf, M, Fn, Dn);
  mgemm_kernel<1><<<gD, blk256, 0, stream>>>(hbf, wt_fo2, fo_b2, xcur, xcur,
                                             nullptr, M, Dn, Fn);

  // final LN -> d_out[0]
  ln_kernel<0, 0><<<grid_rows, blk256, 0, stream>>>(xcur, fl_g, fl_b, out,
                                                    nullptr, nullptr, nullptr);

  // passthrough: pos_k (only if not fused into bmm), mask convert (always)
  if (!fused)
    hipMemcpyAsync(out + N_OUT, pos_k, N_POSK * sizeof(float),
                   hipMemcpyDeviceToDevice, stream);
  i2f_kernel<<<dim3((N_MASK / 4 + 255) / 256), blk256, 0, stream>>>(
      mask, out + N_OUT + N_POSK, N_MASK / 4);
}

// Round 7
// 402.772 us; speedup vs baseline: 12.1102x; 1.2584x over previous
//
#include <hip/hip_runtime.h>
#include <math.h>

static constexpr int Bsz = 4, Tn = 1024, Dn = 512, Hn = 8, Fn = 2048, Kw = 31, Dk = 64;
static constexpr size_t N_OUT  = (size_t)Bsz * Tn * Dn;   // 2,097,152
static constexpr size_t N_POSK = (size_t)Tn * Tn * Dk;    // 67,108,864
static constexpr size_t N_MASK = (size_t)Bsz * Tn * Tn;   // 4,194,304

typedef __attribute__((ext_vector_type(8))) short bhalf8;  // 8 bf16 (4 VGPR)
typedef __attribute__((ext_vector_type(4))) float f4;      // MFMA C/D

__device__ __forceinline__ ushort f2b(float f) {
  uint b = __float_as_uint(f);
  uint r = (b + 0x7FFFu + ((b >> 16) & 1u)) >> 16;
  return (ushort)r;
}
__device__ __forceinline__ float b2f(ushort u) {
  return __uint_as_float((uint)u << 16);
}

// async global->LDS, 16 B per lane
typedef const __attribute__((address_space(1))) unsigned int* gp1_t;
typedef __attribute__((address_space(3))) unsigned int* lp3_t;
__device__ __forceinline__ void gload16(const void* g, void* l) {
  __builtin_amdgcn_global_load_lds((gp1_t)g, (lp3_t)l, 16, 0, 0);
}

// ---------------------------------------------------------------------------
// LayerNorm; BF=1 -> bf16 output, BF=0 -> fp32 output. GLU on fp32 path.
// ---------------------------------------------------------------------------
template <int GLU, int BF>
__global__ __launch_bounds__(256) void ln_kernel(
    const float* __restrict__ x, const float* __restrict__ g,
    const float* __restrict__ b, float* __restrict__ yf,
    ushort* __restrict__ yb, const float* __restrict__ pw1w,
    const float* __restrict__ pw1b) {
  const int row = blockIdx.x;
  const float* xr = x + (size_t)row * Dn;
  const int tid = threadIdx.x, wid = tid >> 6, lane = tid & 63;

  __shared__ float red[4];
  __shared__ float bc[2];

  float v0 = xr[tid], v1 = xr[tid + 256];
  float s = v0 + v1;
#pragma unroll
  for (int off = 32; off; off >>= 1) s += __shfl_xor(s, off);
  if (lane == 0) red[wid] = s;
  __syncthreads();
  if (tid == 0) bc[0] = (red[0] + red[1] + red[2] + red[3]) * (1.0f / Dn);
  __syncthreads();
  const float m = bc[0];
  const float d0 = v0 - m, d1 = v1 - m;
  float s2 = d0 * d0 + d1 * d1;
#pragma unroll
  for (int off = 32; off; off >>= 1) s2 += __shfl_xor(s2, off);
  if (lane == 0) red[wid] = s2;
  __syncthreads();
  if (tid == 0)
    bc[1] = rsqrtf((red[0] + red[1] + red[2] + red[3]) * (1.0f / Dn) + 1e-5f);
  __syncthreads();
  const float r = bc[1];

  float o0 = d0 * r * g[tid] + b[tid];
  float o1 = d1 * r * g[tid + 256] + b[tid + 256];
  if (GLU) {
    const float w0 = pw1w[0], w1 = pw1w[1], c0 = pw1b[0], c1 = pw1b[1];
    o0 = (w0 * o0 + c0) * (1.0f / (1.0f + expf(-(w1 * o0 + c1))));
    o1 = (w0 * o1 + c0) * (1.0f / (1.0f + expf(-(w1 * o1 + c1))));
  }
  if (BF) {
    yb[(size_t)row * Dn + tid] = f2b(o0);
    yb[(size_t)row * Dn + tid + 256] = f2b(o1);
  } else {
    yf[(size_t)row * Dn + tid] = o0;
    yf[(size_t)row * Dn + tid + 256] = o1;
  }
}

// ---------------------------------------------------------------------------
// Weight convert+transpose: W (K x N fp32, row-major) -> Wt (N x K bf16)
// ---------------------------------------------------------------------------
__global__ __launch_bounds__(256) void wcvt_kernel(const float* __restrict__ W,
                                                   ushort* __restrict__ Wt,
                                                   int K, int N) {
  __shared__ float tile[32][33];
  const int n0 = blockIdx.x * 32, k0 = blockIdx.y * 32;
  const int tx = threadIdx.x & 31, ty = threadIdx.x >> 5;
#pragma unroll
  for (int i = 0; i < 4; ++i) {
    int k = ty + i * 8;
    tile[k][tx] = W[(size_t)(k0 + k) * N + n0 + tx];
  }
  __syncthreads();
#pragma unroll
  for (int i = 0; i < 4; ++i) {
    int r = ty + i * 8;
    Wt[(size_t)(n0 + r) * K + k0 + tx] = f2b(tile[tx][r]);
  }
}

// ---------------------------------------------------------------------------
// bf16 MFMA GEMM (NT), tile TM x TM, 4 waves (2x2), wave tile TM/2.
// MODE 0: relu -> bf16 Cb     MODE 1: C = res + 0.5*v (fp32)
// MODE 3: C = res + v (fp32)  MODE 4: Cb = bf16(v)
// ---------------------------------------------------------------------------
template <int MODE, int TM>
__global__ __launch_bounds__(256) void mgemm_kernel(
    const ushort* __restrict__ A, const ushort* __restrict__ Bt,
    const float* __restrict__ bias, const float* __restrict__ res,
    float* __restrict__ C, ushort* __restrict__ Cb, int M, int N, int K) {
  constexpr int WT = TM / 2;   // wave tile
  constexpr int NF = WT / 16;  // frags per dim
  __shared__ ushort As[TM * 64];
  __shared__ ushort Bs[TM * 64];
  const int bm = blockIdx.y * TM, bn = blockIdx.x * TM;
  const int tid = threadIdx.x;
  const int wid = tid >> 6, l = tid & 63;
  const int wm = wid >> 1, wn = wid & 1;
  const int l16 = l & 15, lhi = l >> 4;

  f4 acc[NF][NF] = {};

  for (int k0 = 0; k0 < K; k0 += 64) {
#pragma unroll
    for (int i = 0; i < TM * 8 / 256; ++i) {
      int slot = tid + i * 256;
      int row = slot >> 3, c8 = slot & 7;
      gload16(A + (size_t)(bm + row) * K + k0 + c8 * 8, &As[slot * 8]);
      gload16(Bt + (size_t)(bn + row) * K + k0 + c8 * 8, &Bs[slot * 8]);
    }
    __syncthreads();
#pragma unroll
    for (int ks = 0; ks < 2; ++ks) {
      bhalf8 a[NF], b[NF];
#pragma unroll
      for (int mi = 0; mi < NF; ++mi)
        a[mi] = *(const bhalf8*)&As[(wm * WT + mi * 16 + l16) * 64 + ks * 32 +
                                    lhi * 8];
#pragma unroll
      for (int ni = 0; ni < NF; ++ni)
        b[ni] = *(const bhalf8*)&Bs[(wn * WT + ni * 16 + l16) * 64 + ks * 32 +
                                    lhi * 8];
#pragma unroll
      for (int mi = 0; mi < NF; ++mi)
#pragma unroll
        for (int ni = 0; ni < NF; ++ni)
          acc[mi][ni] = __builtin_amdgcn_mfma_f32_16x16x32_bf16(
              a[mi], b[ni], acc[mi][ni], 0, 0, 0);
    }
    __syncthreads();
  }

#pragma unroll
  for (int mi = 0; mi < NF; ++mi) {
#pragma unroll
    for (int ni = 0; ni < NF; ++ni) {
      const int col = bn + wn * WT + ni * 16 + l16;
      const float bv = bias[col];
#pragma unroll
      for (int r = 0; r < 4; ++r) {
        const int row = bm + wm * WT + mi * 16 + lhi * 4 + r;
        float v = acc[mi][ni][r] + bv;
        const size_t off = (size_t)row * N + col;
        if (MODE == 0) {
          Cb[off] = f2b(fmaxf(v, 0.0f));
        } else if (MODE == 4) {
          Cb[off] = f2b(v);
        } else {
          if (MODE == 1) v = res[off] + 0.5f * v;
          if (MODE == 3) v = res[off] + v;
          C[off] = v;
        }
      }
    }
  }
}

// ---------------------------------------------------------------------------
// bmm: Sc16[bh][t][s] = bf16( q . pos_k[t,s,:] ); PASS=1 also writes the
// pos_k passthrough copy (reads pos_k exactly once).
// ---------------------------------------------------------------------------
template <int PASS>
__global__ __launch_bounds__(256) void bmm_kernel(const ushort* __restrict__ qbf,
                                                  const float* __restrict__ pk,
                                                  ushort* __restrict__ Sc16,
                                                  float* __restrict__ pkout) {
  const int s0 = blockIdx.x * 256;
  const int t = blockIdx.y;
  const int tid = threadIdx.x, wid = tid >> 6, l = tid & 63;
  const int l16 = l & 15, lhi = l >> 4;

  __shared__ ushort Qs[32 * 64];
  __shared__ ushort Ps[256 * 64];

  {
    int row = tid >> 3, c8 = tid & 7;
    int bq = row >> 3, hq = row & 7;
    *(uint4*)&Qs[row * 64 + c8 * 8] =
        *(const uint4*)(qbf + ((size_t)(bq * Tn + t)) * Dn + hq * 64 + c8 * 8);
  }
#pragma unroll
  for (int i = 0; i < 16; ++i) {
    int slot = tid + i * 256;
    int sr = slot >> 4, c4 = slot & 15;
    const size_t goff = ((size_t)t * Tn + s0 + sr) * Dk + c4 * 4;
    const float4 p = *(const float4*)(pk + goff);
    if (PASS) *(float4*)(pkout + goff) = p;
    ushort4 u;
    u.x = f2b(p.x);
    u.y = f2b(p.y);
    u.z = f2b(p.z);
    u.w = f2b(p.w);
    *(ushort4*)&Ps[sr * 64 + c4 * 4] = u;
  }
  __syncthreads();

  f4 acc[2][4] = {};
#pragma unroll
  for (int ks = 0; ks < 2; ++ks) {
    bhalf8 a[2], b[4];
#pragma unroll
    for (int mi = 0; mi < 2; ++mi)
      a[mi] = *(const bhalf8*)&Qs[(mi * 16 + l16) * 64 + ks * 32 + lhi * 8];
#pragma unroll
    for (int ni = 0; ni < 4; ++ni)
      b[ni] = *(const bhalf8*)&Ps[(wid * 64 + ni * 16 + l16) * 64 + ks * 32 +
                                  lhi * 8];
#pragma unroll
    for (int mi = 0; mi < 2; ++mi)
#pragma unroll
      for (int ni = 0; ni < 4; ++ni)
        acc[mi][ni] = __builtin_amdgcn_mfma_f32_16x16x32_bf16(
            a[mi], b[ni], acc[mi][ni], 0, 0, 0);
  }

#pragma unroll
  for (int mi = 0; mi < 2; ++mi)
#pragma unroll
    for (int ni = 0; ni < 4; ++ni)
#pragma unroll
      for (int r = 0; r < 4; ++r) {
        const int bh = mi * 16 + lhi * 4 + r;
        const int s = s0 + wid * 64 + ni * 16 + l16;
        Sc16[((size_t)bh * Tn + t) * Tn + s] = f2b(acc[mi][ni][r]);
      }
}

// ---------------------------------------------------------------------------
// fattn: flash attention. Per block: 128 t rows x one bh. Iterate 128-s tiles:
// acc = Bm (from Sc16, C-layout global u16 loads) + Q.K^T (MFMA); *scale;
// masked via packed bits; online softmax (regs); P->LDS (XOR swizzle); PV.
// ---------------------------------------------------------------------------
__global__ __launch_bounds__(256) void fattn_kernel(
    const ushort* __restrict__ qbf, const ushort* __restrict__ kbf,
    const ushort* __restrict__ vbf, const ushort* __restrict__ Sc16,
    const uint* __restrict__ mbits, ushort* __restrict__ ctxb) {
  const int bh = blockIdx.y;
  const int b = bh >> 3, h = bh & 7;
  const int t0 = blockIdx.x * 128;
  const int tid = threadIdx.x;
  const int wid = tid >> 6, l = tid & 63;
  const int l16 = l & 15, lhi = l >> 4;

  __shared__ ushort KV[64 * 132];   // K tile [s][64] / V^T [d][132]
  __shared__ ushort Ps[128 * 128];  // P (swizzled); also Q staging

  // Q fragments -> registers (staged via Ps)
  bhalf8 qa[2][2];
  {
#pragma unroll
    for (int i = 0; i < 4; ++i) {
      int slot = tid + i * 256;
      int row = slot >> 3, c8 = slot & 7;
      gload16(qbf + ((size_t)(b * Tn + t0 + row)) * Dn + h * 64 + c8 * 8,
              &Ps[slot * 8]);
    }
    __syncthreads();
#pragma unroll
    for (int mi = 0; mi < 2; ++mi)
#pragma unroll
      for (int ks = 0; ks < 2; ++ks)
        qa[mi][ks] = *(const bhalf8*)&Ps[(wid * 32 + mi * 16 + l16) * 64 +
                                         ks * 32 + lhi * 8];
    __syncthreads();
  }

  f4 oacc[2][4] = {};
  float mrow[2][4], lrow[2][4];
#pragma unroll
  for (int mi = 0; mi < 2; ++mi)
#pragma unroll
    for (int r = 0; r < 4; ++r) {
      mrow[mi][r] = -3.0e38f;
      lrow[mi][r] = 0.0f;
    }

  const float scale = 0.125f;
  for (int s0 = 0; s0 < Tn; s0 += 128) {
    // stage K [128 s][64 dk]
#pragma unroll
    for (int i = 0; i < 2; ++i) {
      int slot = tid + i * 256;
      int row = slot >> 3, c8 = slot & 7;
      gload16(kbf + ((size_t)(b * Tn + s0 + row)) * Dn + h * 64 + c8 * 8,
              &KV[slot * 8]);
    }
    // acc init = Bm (C-layout direct global loads)
    f4 accs[2][8];
#pragma unroll
    for (int mi = 0; mi < 2; ++mi)
#pragma unroll
      for (int r = 0; r < 4; ++r) {
        const int trow = t0 + wid * 32 + mi * 16 + lhi * 4 + r;
        const ushort* src = Sc16 + ((size_t)bh * Tn + trow) * Tn + s0;
#pragma unroll
        for (int ni = 0; ni < 8; ++ni) accs[mi][ni][r] = b2f(src[ni * 16 + l16]);
      }
    __syncthreads();  // K visible

    // QK^T
#pragma unroll
    for (int ks = 0; ks < 2; ++ks) {
      bhalf8 bb[8];
#pragma unroll
      for (int ni = 0; ni < 8; ++ni)
        bb[ni] = *(const bhalf8*)&KV[(ni * 16 + l16) * 64 + ks * 32 + lhi * 8];
#pragma unroll
      for (int mi = 0; mi < 2; ++mi)
#pragma unroll
        for (int ni = 0; ni < 8; ++ni)
          accs[mi][ni] = __builtin_amdgcn_mfma_f32_16x16x32_bf16(
              qa[mi][ks], bb[ni], accs[mi][ni], 0, 0, 0);
    }

    // online softmax (in regs) + P write (swizzled)
#pragma unroll
    for (int mi = 0; mi < 2; ++mi)
#pragma unroll
      for (int r = 0; r < 4; ++r) {
        const int trow = t0 + wid * 32 + mi * 16 + lhi * 4 + r;
        const uint* mw = mbits + ((size_t)b * Tn + trow) * 32 + (s0 >> 5);
        const uint w[4] = {mw[0], mw[1], mw[2], mw[3]};
        float p[8];
        float rm = -3.0e38f;
#pragma unroll
        for (int ni = 0; ni < 8; ++ni) {
          float v = accs[mi][ni][r] * scale;
          const uint bit = (w[ni >> 1] >> ((ni & 1) * 16 + l16)) & 1u;
          v = bit ? v : -3.0e38f;
          p[ni] = v;
          rm = fmaxf(rm, v);
        }
#pragma unroll
        for (int off = 8; off; off >>= 1) rm = fmaxf(rm, __shfl_xor(rm, off));
        const float mnew = fmaxf(mrow[mi][r], rm);
        const float sold = __expf(mrow[mi][r] - mnew);
        mrow[mi][r] = mnew;
        float rs = 0.0f;
#pragma unroll
        for (int ni = 0; ni < 8; ++ni) {
          const float e = __expf(p[ni] - mnew);
          rs += e;
          p[ni] = e;
        }
#pragma unroll
        for (int off = 8; off; off >>= 1) rs += __shfl_xor(rs, off);
        lrow[mi][r] = lrow[mi][r] * sold + rs;
#pragma unroll
        for (int ni = 0; ni < 4; ++ni) oacc[mi][ni][r] *= sold;
        const int lr = wid * 32 + mi * 16 + lhi * 4 + r;
#pragma unroll
        for (int ni = 0; ni < 8; ++ni) {
          const int byte =
              (lr * 256 + (ni * 16 + l16) * 2) ^ ((lr & 7) << 4);
          *(ushort*)((char*)Ps + byte) = f2b(p[ni]);
        }
      }
    __syncthreads();  // QK done reading KV; P written

    // stage V^T [d][s]
#pragma unroll
    for (int i = 0; i < 2; ++i) {
      int slot = tid + i * 256;
      int sr = slot >> 3, c8 = slot & 7;
      const uint4 raw = *(const uint4*)(
          vbf + ((size_t)(b * Tn + s0 + sr)) * Dn + h * 64 + c8 * 8);
      const ushort* e = (const ushort*)&raw;
#pragma unroll
      for (int j = 0; j < 8; ++j) KV[(c8 * 8 + j) * 132 + sr] = e[j];
    }
    __syncthreads();  // V^T + P visible

    // PV
#pragma unroll
    for (int ks = 0; ks < 4; ++ks) {
      bhalf8 a[2], bb[4];
#pragma unroll
      for (int mi = 0; mi < 2; ++mi) {
        const int lr = wid * 32 + mi * 16 + l16;
        const int byte = (lr * 256 + ks * 64 + lhi * 16) ^ ((lr & 7) << 4);
        a[mi] = *(const bhalf8*)((char*)Ps + byte);
      }
#pragma unroll
      for (int ni = 0; ni < 4; ++ni)
        bb[ni] = *(const bhalf8*)&KV[(ni * 16 + l16) * 132 + ks * 32 + lhi * 8];
#pragma unroll
      for (int mi = 0; mi < 2; ++mi)
#pragma unroll
        for (int ni = 0; ni < 4; ++ni)
          oacc[mi][ni] = __builtin_amdgcn_mfma_f32_16x16x32_bf16(
              a[mi], bb[ni], oacc[mi][ni], 0, 0, 0);
    }
    __syncthreads();  // protect KV/Ps for next iter
  }

#pragma unroll
  for (int mi = 0; mi < 2; ++mi)
#pragma unroll
    for (int r = 0; r < 4; ++r) {
      const float inv = (mrow[mi][r] <= -1.0e37f)
                            ? 0.0f
                            : 1.0f / fmaxf(lrow[mi][r], 1e-30f);
      const int t = t0 + wid * 32 + mi * 16 + lhi * 4 + r;
#pragma unroll
      for (int ni = 0; ni < 4; ++ni) {
        const int d = ni * 16 + l16;
        ctxb[((size_t)(b * Tn + t)) * Dn + h * 64 + d] =
            f2b(oacc[mi][ni][r] * inv);
      }
    }
}

// ---------------------------------------------------------------------------
// conv2: depthwise conv1d (K=31) + ReLU + pw2 + residual; register window.
// ---------------------------------------------------------------------------
__global__ __launch_bounds__(256) void conv2_kernel(
    const float* __restrict__ y, const float* __restrict__ dww,
    const float* __restrict__ dwb, const float* __restrict__ pw2w,
    const float* __restrict__ pw2b, float* __restrict__ x) {
  const int b = blockIdx.z;
  const int d0 = blockIdx.y * 256;
  const int t0 = blockIdx.x * 16;
  const int tid = threadIdx.x;
  const int d = d0 + tid;

  __shared__ float wlds[256 * Kw];
#pragma unroll
  for (int i = 0; i < Kw; ++i)
    wlds[i * 256 + tid] = dww[(size_t)d0 * Kw + i * 256 + tid];
  __syncthreads();

  float w[Kw];
#pragma unroll
  for (int k = 0; k < Kw; ++k) w[k] = wlds[tid * Kw + k];

  float v[46];
#pragma unroll
  for (int i = 0; i < 46; ++i) {
    int t = t0 - 15 + i;
    v[i] = (t >= 0 && t < Tn) ? y[((size_t)b * Tn + t) * Dn + d] : 0.0f;
  }

  const float bias = dwb[d], w2 = pw2w[0], c2 = pw2b[0];
#pragma unroll
  for (int j = 0; j < 16; ++j) {
    float acc = bias;
#pragma unroll
    for (int k = 0; k < Kw; ++k) acc += w[k] * v[j + k];
    acc = fmaxf(acc, 0.0f);
    const size_t idx = ((size_t)b * Tn + t0 + j) * Dn + d;
    x[idx] = x[idx] + w2 * acc + c2;
  }
}

// ---------------------------------------------------------------------------
// maskcvt: int32 mask -> fp32 passthrough output AND packed bits (1 bit/s).
// One thread per 32 elements.
// ---------------------------------------------------------------------------
__global__ __launch_bounds__(256) void maskcvt_kernel(
    const int* __restrict__ in, float* __restrict__ outf,
    uint* __restrict__ mbits) {
  const size_t idx = (size_t)blockIdx.x * 256 + threadIdx.x;
  const size_t base = idx * 32;
  uint bits = 0;
#pragma unroll
  for (int j = 0; j < 8; ++j) {
    const int4 v = *(const int4*)(in + base + j * 4);
    float4 f;
    f.x = (float)v.x;
    f.y = (float)v.y;
    f.z = (float)v.z;
    f.w = (float)v.w;
    *(float4*)(outf + base + j * 4) = f;
    bits |= (v.x != 0 ? 1u : 0u) << (j * 4 + 0);
    bits |= (v.y != 0 ? 1u : 0u) << (j * 4 + 1);
    bits |= (v.z != 0 ? 1u : 0u) << (j * 4 + 2);
    bits |= (v.w != 0 ? 1u : 0u) << (j * 4 + 3);
  }
  mbits[idx] = bits;
}

// ---------------------------------------------------------------------------
extern "C" void kernel_launch(void* const* d_in, const int* in_sizes, int n_in,
                              void* d_out, int out_size, void* d_ws,
                              size_t ws_size, hipStream_t stream) {
  const float* x = (const float*)d_in[0];
  const float* pos_k = (const float*)d_in[1];
  const int* mask = (const int*)d_in[2];
  const float* fi_g = (const float*)d_in[3];
  const float* fi_b = (const float*)d_in[4];
  const float* fi_w1 = (const float*)d_in[5];
  const float* fi_b1 = (const float*)d_in[6];
  const float* fi_w2 = (const float*)d_in[7];
  const float* fi_b2 = (const float*)d_in[8];
  const float* at_g = (const float*)d_in[9];
  const float* at_b = (const float*)d_in[10];
  const float* wq = (const float*)d_in[11];
  const float* bq = (const float*)d_in[12];
  const float* wk = (const float*)d_in[13];
  const float* bk = (const float*)d_in[14];
  const float* wv = (const float*)d_in[15];
  const float* bv = (const float*)d_in[16];
  const float* wo = (const float*)d_in[17];
  const float* bo = (const float*)d_in[18];
  const float* cv_g = (const float*)d_in[19];
  const float* cv_b = (const float*)d_in[20];
  const float* pw1w = (const float*)d_in[21];
  const float* pw1b = (const float*)d_in[22];
  const float* dww = (const float*)d_in[23];
  const float* dwb = (const float*)d_in[24];
  const float* pw2w = (const float*)d_in[25];
  const float* pw2b = (const float*)d_in[26];
  const float* fo_g = (const float*)d_in[27];
  const float* fo_b = (const float*)d_in[28];
  const float* fo_w1 = (const float*)d_in[29];
  const float* fo_b1 = (const float*)d_in[30];
  const float* fo_w2 = (const float*)d_in[31];
  const float* fo_b2 = (const float*)d_in[32];
  const float* fl_g = (const float*)d_in[33];
  const float* fl_b = (const float*)d_in[34];

  float* out = (float*)d_out;

  // ws front: xcur | y | mbits (always; ~34.6 MB)
  float* xcur = (float*)d_ws;
  float* y = xcur + N_OUT;
  uint* mbits = (uint*)(y + N_OUT);  // N_MASK/32 uints = 512 KB

  // big scratch: prefer ws (enables fused pos_k passthrough); else out region
  const size_t NEED = (size_t)206 << 20;
  const bool fused = ws_size >= NEED;
  char* sp = fused ? (char*)(mbits + N_MASK / 32) : (char*)(out + N_OUT);
  auto alloc16 = [&](size_t elems) {
    ushort* p = (ushort*)sp;
    sp += ((elems * 2 + 255) & ~(size_t)255);
    return p;
  };
  ushort* Sc16 = alloc16((size_t)32 * Tn * Tn);  // 67 MB
  ushort* wt_fi1 = alloc16((size_t)Fn * Dn);
  ushort* wt_fi2 = alloc16((size_t)Dn * Fn);
  ushort* wt_q = alloc16((size_t)Dn * Dn);
  ushort* wt_k = alloc16((size_t)Dn * Dn);
  ushort* wt_v = alloc16((size_t)Dn * Dn);
  ushort* wt_o = alloc16((size_t)Dn * Dn);
  ushort* wt_fo1 = alloc16((size_t)Fn * Dn);
  ushort* wt_fo2 = alloc16((size_t)Dn * Fn);
  ushort* ybf = alloc16(N_OUT);
  ushort* hbf = alloc16((size_t)Bsz * Tn * Fn);
  ushort* ctxbf = alloc16(N_OUT);
  ushort* qbf = alloc16(N_OUT);
  ushort* kbf = alloc16(N_OUT);
  ushort* vbf = alloc16(N_OUT);

  const int M = Bsz * Tn;  // 4096
  const dim3 blk256(256);
  const dim3 grid_rows(M);
  const dim3 gF(Fn / 128, M / 128);  // 128x128 tiles, N=2048
  const dim3 gD64(Dn / 64, M / 64);  // 64x64 tiles, N=512 -> 512 blocks

  hipMemcpyAsync(xcur, x, N_OUT * sizeof(float), hipMemcpyDeviceToDevice,
                 stream);

  // mask passthrough + bit-pack (early; flash needs mbits)
  maskcvt_kernel<<<dim3(N_MASK / 32 / 256), blk256, 0, stream>>>(
      mask, out + N_OUT + N_POSK, mbits);

  // weight conversions (fp32 KxN -> bf16 NxK)
  wcvt_kernel<<<dim3(Fn / 32, Dn / 32), blk256, 0, stream>>>(fi_w1, wt_fi1, Dn, Fn);
  wcvt_kernel<<<dim3(Dn / 32, Fn / 32), blk256, 0, stream>>>(fi_w2, wt_fi2, Fn, Dn);
  wcvt_kernel<<<dim3(Dn / 32, Dn / 32), blk256, 0, stream>>>(wq, wt_q, Dn, Dn);
  wcvt_kernel<<<dim3(Dn / 32, Dn / 32), blk256, 0, stream>>>(wk, wt_k, Dn, Dn);
  wcvt_kernel<<<dim3(Dn / 32, Dn / 32), blk256, 0, stream>>>(wv, wt_v, Dn, Dn);
  wcvt_kernel<<<dim3(Dn / 32, Dn / 32), blk256, 0, stream>>>(wo, wt_o, Dn, Dn);
  wcvt_kernel<<<dim3(Fn / 32, Dn / 32), blk256, 0, stream>>>(fo_w1, wt_fo1, Dn, Fn);
  wcvt_kernel<<<dim3(Dn / 32, Fn / 32), blk256, 0, stream>>>(fo_w2, wt_fo2, Fn, Dn);

  // macaron FFN-in
  ln_kernel<0, 1><<<grid_rows, blk256, 0, stream>>>(xcur, fi_g, fi_b, nullptr,
                                                    ybf, nullptr, nullptr);
  mgemm_kernel<0, 128><<<gF, blk256, 0, stream>>>(ybf, wt_fi1, fi_b1, nullptr,
                                                  nullptr, hbf, M, Fn, Dn);
  mgemm_kernel<1, 64><<<gD64, blk256, 0, stream>>>(hbf, wt_fi2, fi_b2, xcur,
                                                   xcur, nullptr, M, Dn, Fn);

  // attention projections (bf16 outputs)
  ln_kernel<0, 1><<<grid_rows, blk256, 0, stream>>>(xcur, at_g, at_b, nullptr,
                                                    ybf, nullptr, nullptr);
  mgemm_kernel<4, 64><<<gD64, blk256, 0, stream>>>(ybf, wt_q, bq, nullptr,
                                                   nullptr, qbf, M, Dn, Dn);
  mgemm_kernel<4, 64><<<gD64, blk256, 0, stream>>>(ybf, wt_k, bk, nullptr,
                                                   nullptr, kbf, M, Dn, Dn);
  mgemm_kernel<4, 64><<<gD64, blk256, 0, stream>>>(ybf, wt_v, bv, nullptr,
                                                   nullptr, vbf, M, Dn, Dn);

  if (fused)
    bmm_kernel<1><<<dim3(4, Tn), blk256, 0, stream>>>(qbf, pos_k, Sc16,
                                                      out + N_OUT);
  else
    bmm_kernel<0><<<dim3(4, Tn), blk256, 0, stream>>>(qbf, pos_k, Sc16,
                                                      nullptr);

  fattn_kernel<<<dim3(Tn / 128, 32), blk256, 0, stream>>>(qbf, kbf, vbf, Sc16,
                                                          mbits, ctxbf);

  mgemm_kernel<3, 64><<<gD64, blk256, 0, stream>>>(ctxbf, wt_o, bo, xcur, xcur,
                                                   nullptr, M, Dn, Dn);

  // conv module
  ln_kernel<1, 0><<<grid_rows, blk256, 0, stream>>>(xcur, cv_g, cv_b, y,
                                                    nullptr, pw1w, pw1b);
  conv2_kernel<<<dim3(Tn / 16, 2, Bsz), blk256, 0, stream>>>(y, dww, dwb, pw2w,
                                                             pw2b, xcur);

  // macaron FFN-out
  ln_kernel<0, 1><<<grid_rows, blk256, 0, stream>>>(xcur, fo_g, fo_b, nullptr,
                                                    ybf, nullptr, nullptr);
  mgemm_kernel<0, 128><<<gF, blk256, 0, stream>>>(ybf, wt_fo1, fo_b1, nullptr,
                                                  nullptr, hbf, M, Fn, Dn);
  mgemm_kernel<1, 64><<<gD64, blk256, 0, stream>>>(hbf, wt_fo2, fo_b2, xcur,
                                                   xcur, nullptr, M, Dn, Fn);

  // final LN -> d_out[0]
  ln_kernel<0, 0><<<grid_rows, blk256, 0, stream>>>(xcur, fl_g, fl_b, out,
                                                    nullptr, nullptr, nullptr);

  // pos_k passthrough (only if not fused into bmm)
  if (!fused)
    hipMemcpyAsync(out + N_OUT, pos_k, N_POSK * sizeof(float),
                   hipMemcpyDeviceToDevice, stream);
}